// Round 3
// baseline (452.765 us; speedup 1.0000x reference)
//
#include <hip/hip_runtime.h>

__device__ __forceinline__ float sgm(float x) { return 1.f / (1.f + __expf(-x)); }

// thread k owns z-rows {k, 32+k, 64+k, 96+k} -> gates i,f,g,o for cell k all local.
// LDS weights f32, no padding; pair-index XOR swizzle: pair p of row r stored at
// float offset r*32 + 2*(p ^ (r&15)).  Read: 32 lanes hit 16 distinct bank-pairs
// (k and k+16 alias) -> 2-way, free.  Total 4 x 16 KB = 64 KB exactly.
__device__ __forceinline__ void lstm_step(
    const float* __restrict__ sWi, const float* __restrict__ sWh,
    float bzi, float bzf, float bzg, float bzo,
    const float (&xf)[32], float (&hf)[32], float& cst, int k, int lb)
{
    float zi = bzi, zf = bzf, zg = bzg, zo = bzo;
    const int sw = k & 15;
    #pragma unroll
    for (int c2 = 0; c2 < 16; c2++) {
        const int col = 2 * (c2 ^ sw);             // swizzled LDS column
        float xa = xf[2*c2], xb = xf[2*c2+1];
        float ha = hf[2*c2], hb = hf[2*c2+1];
        float2 wiA = *(const float2*)&sWi[(0  + k)*32 + col];
        float2 whA = *(const float2*)&sWh[(0  + k)*32 + col];
        zi += wiA.x*xa + wiA.y*xb + whA.x*ha + whA.y*hb;
        float2 wiB = *(const float2*)&sWi[(32 + k)*32 + col];
        float2 whB = *(const float2*)&sWh[(32 + k)*32 + col];
        zf += wiB.x*xa + wiB.y*xb + whB.x*ha + whB.y*hb;
        float2 wiC = *(const float2*)&sWi[(64 + k)*32 + col];
        float2 whC = *(const float2*)&sWh[(64 + k)*32 + col];
        zg += wiC.x*xa + wiC.y*xb + whC.x*ha + whC.y*hb;
        float2 wiD = *(const float2*)&sWi[(96 + k)*32 + col];
        float2 whD = *(const float2*)&sWh[(96 + k)*32 + col];
        zo += wiD.x*xa + wiD.y*xb + whD.x*ha + whD.y*hb;
    }
    float ig = sgm(zi)*tanhf(zg);
    cst = sgm(zf)*cst + ig;
    float hl = sgm(zo)*tanhf(cst);
    #pragma unroll
    for (int d = 0; d < 32; d++) hf[d] = __shfl(hl, lb + d, 64);
}

// One fused kernel: GAT (g recomputed on the fly) + LSTM x2 + FC. Zero d_ws use.
// 256 thr = 8 seqs x 32 lanes. grid = 300 -> 2400 seqs.
__global__ __launch_bounds__(256) void k_fused(
    const float* __restrict__ A,    const float* __restrict__ X,
    const float* __restrict__ Wg,   const float* __restrict__ aat,
    const float* __restrict__ Wih0, const float* __restrict__ Whh0,
    const float* __restrict__ bih0, const float* __restrict__ bhh0,
    const float* __restrict__ Wih1, const float* __restrict__ Whh1,
    const float* __restrict__ bih1, const float* __restrict__ bhh1,
    const float* __restrict__ fcW,  const float* __restrict__ fcb,
    float* __restrict__ out)
{
    __shared__ float sW0i[4096], sW0h[4096], sW1i[4096], sW1h[4096];  // 64 KB

    const int tid = threadIdx.x;
    for (int x2 = tid; x2 < 2048; x2 += 256) {
        int r = x2 >> 4, p = x2 & 15;
        int o = r*32 + 2*(p ^ (r & 15));
        *(float2*)&sW0i[o] = *(const float2*)&Wih0[r*32 + 2*p];
        *(float2*)&sW0h[o] = *(const float2*)&Whh0[r*32 + 2*p];
        *(float2*)&sW1i[o] = *(const float2*)&Wih1[r*32 + 2*p];
        *(float2*)&sW1h[o] = *(const float2*)&Whh1[r*32 + 2*p];
    }

    const int w   = tid >> 5;        // seq slot in block
    const int k   = tid & 31;        // lane within seq (owns hid component k)
    const int lb  = tid & 32;        // lane base within wave (2 seqs per wave)
    const int seq = blockIdx.x * 8 + w;
    const int b   = seq / 300, i = seq % 300;

    // ---- neighbor list of node i, kept in registers (capacity 64) ----
    // lane (s&31) holds slot s in nb0 (s<32) / nb1 (s>=32)
    int nb0 = 0, nb1 = 0, cnt = 0;
    for (int j0 = 0; j0 < 300; j0 += 32) {
        int j = j0 + k;
        bool p = (j < 300) && (A[i*300 + j] != 0.f);
        unsigned long long m64 = __ballot(p);
        unsigned mm = (unsigned)(m64 >> lb);       // this seq's 32 bits (uniform)
        while (mm) {
            int bpos = __ffs(mm) - 1;
            if ((cnt & 31) == k && cnt < 64) {
                if (cnt & 32) nb1 = j0 + bpos; else nb0 = j0 + bpos;
            }
            cnt++;
            mm &= mm - 1;
        }
    }
    if (cnt > 64) cnt = 64;

    // ---- per-thread constants ----
    const int dd = k & 3;                          // d within head (h = k>>2)
    float wg0 = Wg[k*3+0], wg1 = Wg[k*3+1], wg2 = Wg[k*3+2];
    float alv = aat[dd],   arv = aat[4+dd];
    float b0i = bih0[k]    + bhh0[k];
    float b0f = bih0[32+k] + bhh0[32+k];
    float b0g = bih0[64+k] + bhh0[64+k];
    float b0o = bih0[96+k] + bhh0[96+k];
    float b1i = bih1[k]    + bhh1[k];
    float b1f = bih1[32+k] + bhh1[32+k];
    float b1g = bih1[64+k] + bhh1[64+k];
    float b1o = bih1[96+k] + bhh1[96+k];

    __syncthreads();

    float h0f[32], h1f[32];
    #pragma unroll
    for (int d = 0; d < 32; d++) { h0f[d] = 0.f; h1f[d] = 0.f; }
    float c0 = 0.f, c1 = 0.f;

    const size_t xrow = (size_t)(b*300 + i) * 36;

    for (int t = 0; t < 12; t++) {
        // ---- GAT attention for (b, i, t); lane k owns output component k ----
        float gi = wg0*X[xrow + t*3 + 0] + wg1*X[xrow + t*3 + 1]
                 + wg2*X[xrow + t*3 + 2];
        float gl = gi * alv;                       // quad-reduce over d
        gl += __shfl_xor(gl, 1, 64);
        gl += __shfl_xor(gl, 2, 64);

        float m = -1e30f, s = 0.f, acc = 0.f;
        for (int kk = 0; kk < cnt; kk++) {
            int v = (kk & 32) ? nb1 : nb0;         // kk&32 uniform per seq
            int j = __shfl(v, lb + (kk & 31), 64);
            size_t xj = (size_t)(b*300 + j) * 36 + t*3;
            float gj = wg0*X[xj+0] + wg1*X[xj+1] + wg2*X[xj+2];
            float gr = gj * arv;
            gr += __shfl_xor(gr, 1, 64);
            gr += __shfl_xor(gr, 2, 64);
            float e = gl + gr;
            e = e > 0.f ? e : 0.2f*e;              // leaky_relu 0.2
            if (e > m) {                           // online softmax (e,m quad-uniform)
                float sc = __expf(m - e);
                s = s*sc + 1.f; acc = acc*sc + gj; m = e;
            } else {
                float wgt = __expf(e - m);
                s += wgt; acc += wgt*gj;
            }
        }
        float x_k = acc / s;                       // hgat[b,i,t,k]; s >= 1 (self-loop)

        // ---- broadcast hgat vector to all lanes of this seq ----
        float xf[32];
        #pragma unroll
        for (int d = 0; d < 32; d++) xf[d] = __shfl(x_k, lb + d, 64);

        lstm_step(sW0i, sW0h, b0i, b0f, b0g, b0o, xf,  h0f, c0, k, lb);
        lstm_step(sW1i, sW1h, b1i, b1f, b1g, b1o, h0f, h1f, c1, k, lb);
    }

    // ---- FC: out[seq, r] = fcb[r] + fcW[r,:] . h1 ----
    for (int r = k; r < 36; r += 32) {
        float a2 = fcb[r];
        #pragma unroll
        for (int c2 = 0; c2 < 16; c2++) {
            float2 u = *(const float2*)&fcW[r*32 + 2*c2];
            a2 += u.x*h1f[2*c2] + u.y*h1f[2*c2+1];
        }
        out[seq*36 + r] = a2;
    }
}

extern "C" void kernel_launch(void* const* d_in, const int* in_sizes, int n_in,
                              void* d_out, int out_size, void* d_ws, size_t ws_size,
                              hipStream_t stream)
{
    const float* A    = (const float*)d_in[0];
    const float* X    = (const float*)d_in[1];
    const float* Wg   = (const float*)d_in[2];
    const float* aat  = (const float*)d_in[3];
    const float* Wih0 = (const float*)d_in[4];
    const float* Whh0 = (const float*)d_in[5];
    const float* bih0 = (const float*)d_in[6];
    const float* bhh0 = (const float*)d_in[7];
    const float* Wih1 = (const float*)d_in[8];
    const float* Whh1 = (const float*)d_in[9];
    const float* bih1 = (const float*)d_in[10];
    const float* bhh1 = (const float*)d_in[11];
    const float* fcW  = (const float*)d_in[12];
    const float* fcb  = (const float*)d_in[13];
    float* out = (float*)d_out;

    k_fused<<<300, 256, 0, stream>>>(A, X, Wg, aat,
                                     Wih0, Whh0, bih0, bhh0,
                                     Wih1, Whh1, bih1, bhh1,
                                     fcW, fcb, out);
}

// Round 4
// 219.109 us; speedup vs baseline: 2.0664x; 2.0664x over previous
//
#include <hip/hip_runtime.h>

__device__ __forceinline__ float sgm(float x) { return 1.f / (1.f + __expf(-x)); }
__device__ __forceinline__ float tanh_fast(float x) {
    float e = __expf(-2.f * fabsf(x));
    float t = (1.f - e) / (1.f + e);
    return copysignf(t, x);
}

// =================== kernel 0: neighbor lists (one wave per row i) ===================
__global__ void k_nbr(const float* __restrict__ A, int* __restrict__ cnt, int* __restrict__ idx)
{
    int i = blockIdx.x;
    int lane = threadIdx.x;
    int c = 0;
    for (int j0 = 0; j0 < 300; j0 += 64) {
        int j = j0 + lane;
        bool p = (j < 300) && (A[i*300 + j] != 0.f);
        unsigned long long m = __ballot(p);
        if (p) {
            int pos = __popcll(m & ((1ull << lane) - 1ull));
            if (c + pos < 64) idx[i*64 + c + pos] = j;
        }
        c += __popcll(m);
    }
    if (c > 64) c = 64;
    if (lane == 0) cnt[i] = c;
}

// =================== kernel 1: GAT attention -> hgat ===================
// wave per seq=(b,i); lane = (h, j8): 8 heads x 8 j-slots; t-loop inside.
// gr[j,h] = x_j . war[h];  out[h,d] = (sum_j a_j x_j) . Wg[h*4+d,:] / s
__global__ __launch_bounds__(256, 4) void k_attn(
    const float* __restrict__ X, const float* __restrict__ Wg,
    const float* __restrict__ aat, const int* __restrict__ cnt,
    const int* __restrict__ idx, float* __restrict__ hgat)
{
    int seq = blockIdx.x * 4 + (threadIdx.x >> 6);   // 0..2399
    int lane = threadIdx.x & 63;
    int h = lane >> 3, j8 = lane & 7, d = j8 & 3;
    int b = seq / 300, i = seq % 300;

    // wal/war for head h; wproj = Wg row (h*4+d)
    float wal0=0.f, wal1=0.f, wal2=0.f, war0=0.f, war1=0.f, war2=0.f;
    #pragma unroll
    for (int dd = 0; dd < 4; dd++) {
        float av = aat[dd], bv = aat[4+dd];
        const float* wr = Wg + (h*4+dd)*3;
        wal0 += wr[0]*av; wal1 += wr[1]*av; wal2 += wr[2]*av;
        war0 += wr[0]*bv; war1 += wr[1]*bv; war2 += wr[2]*bv;
    }
    const float* wp = Wg + (h*4+d)*3;
    float wp0 = wp[0], wp1 = wp[1], wp2 = wp[2];

    int c = cnt[i];
    int jj[8];
    #pragma unroll
    for (int q = 0; q < 8; q++) jj[q] = idx[i*64 + q*8 + j8];   // guarded by c before use

    const float* Xi = X + (size_t)(b*300 + i) * 36;

    for (int t = 0; t < 12; t++) {
        float x0 = Xi[t*3+0], x1 = Xi[t*3+1], x2 = Xi[t*3+2];
        float gl = x0*wal0 + x1*wal1 + x2*wal2;

        float m = -1e30f, s = 0.f, a0 = 0.f, a1 = 0.f, a2 = 0.f;
        for (int q = 0; q*8 + j8 < c; q++) {
            int j = jj[q];
            const float* Xj = X + (size_t)(b*300 + j) * 36 + t*3;
            float y0 = Xj[0], y1 = Xj[1], y2 = Xj[2];
            float gr = y0*war0 + y1*war1 + y2*war2;
            float e = gl + gr;
            e = e > 0.f ? e : 0.2f*e;              // leaky_relu 0.2
            if (e > m) {
                float sc = __expf(m - e);
                s = s*sc + 1.f;
                a0 = a0*sc + y0; a1 = a1*sc + y1; a2 = a2*sc + y2;
                m = e;
            } else {
                float w = __expf(e - m);
                s += w;
                a0 += w*y0; a1 += w*y1; a2 += w*y2;
            }
        }
        // merge across the 8 j-slots of this head (lane bits 0..2)
        #pragma unroll
        for (int off = 1; off <= 4; off <<= 1) {
            float m2 = __shfl_xor(m, off, 64);
            float s2 = __shfl_xor(s, off, 64);
            float b0 = __shfl_xor(a0, off, 64);
            float b1 = __shfl_xor(a1, off, 64);
            float b2 = __shfl_xor(a2, off, 64);
            float mo = fmaxf(m, m2);
            float w1 = __expf(m - mo), w2 = __expf(m2 - mo);
            s = s*w1 + s2*w2;
            a0 = a0*w1 + b0*w2; a1 = a1*w1 + b1*w2; a2 = a2*w1 + b2*w2;
            m = mo;
        }
        if (j8 < 4) {
            float o = (a0*wp0 + a1*wp1 + a2*wp2) / s;
            hgat[(size_t)(seq*12 + t)*32 + h*4 + d] = o;
        }
    }
}

// =================== kernel 2: LSTM x2 + FC (spill-free) ===================
// 128 thr = 4 seqs x 32 lanes; lane k owns h/c component k and z-rows {k,32+k,64+k,96+k}.
// x/h broadcast via __shfl inside the loop (no [32] register arrays -> no spills).
// Weights in LDS with XOR-pair swizzle (proven 0 bank conflicts), 64 KB exactly.
__device__ __forceinline__ float lstep(
    const float* __restrict__ sWi, const float* __restrict__ sWh,
    float bi, float bf, float bg, float bo,
    float xk, float hk, float& cst, int k, int lb)
{
    float zi = bi, zf = bf, zg = bg, zo = bo;
    const int sw = k & 15;
    #pragma unroll
    for (int c2 = 0; c2 < 16; c2++) {
        float xa = __shfl(xk, lb + 2*c2,     64);
        float xb = __shfl(xk, lb + 2*c2 + 1, 64);
        float ha = __shfl(hk, lb + 2*c2,     64);
        float hb = __shfl(hk, lb + 2*c2 + 1, 64);
        const int col = 2 * (c2 ^ sw);
        float2 wiA = *(const float2*)&sWi[(0  + k)*32 + col];
        float2 whA = *(const float2*)&sWh[(0  + k)*32 + col];
        zi += wiA.x*xa + wiA.y*xb + whA.x*ha + whA.y*hb;
        float2 wiB = *(const float2*)&sWi[(32 + k)*32 + col];
        float2 whB = *(const float2*)&sWh[(32 + k)*32 + col];
        zf += wiB.x*xa + wiB.y*xb + whB.x*ha + whB.y*hb;
        float2 wiC = *(const float2*)&sWi[(64 + k)*32 + col];
        float2 whC = *(const float2*)&sWh[(64 + k)*32 + col];
        zg += wiC.x*xa + wiC.y*xb + whC.x*ha + whC.y*hb;
        float2 wiD = *(const float2*)&sWi[(96 + k)*32 + col];
        float2 whD = *(const float2*)&sWh[(96 + k)*32 + col];
        zo += wiD.x*xa + wiD.y*xb + whD.x*ha + whD.y*hb;
    }
    cst = sgm(zf)*cst + sgm(zi)*tanh_fast(zg);
    return sgm(zo)*tanh_fast(cst);
}

__global__ __launch_bounds__(128, 4) void k_lstm(
    const float* __restrict__ hgat,
    const float* __restrict__ Wih0, const float* __restrict__ Whh0,
    const float* __restrict__ bih0, const float* __restrict__ bhh0,
    const float* __restrict__ Wih1, const float* __restrict__ Whh1,
    const float* __restrict__ bih1, const float* __restrict__ bhh1,
    const float* __restrict__ fcW,  const float* __restrict__ fcb,
    float* __restrict__ out)
{
    __shared__ float sW0i[4096], sW0h[4096], sW1i[4096], sW1h[4096];  // 64 KB exactly

    const int tid = threadIdx.x;
    for (int x2 = tid; x2 < 2048; x2 += 128) {
        int r = x2 >> 4, p = x2 & 15;
        int o = r*32 + 2*(p ^ (r & 15));
        *(float2*)&sW0i[o] = *(const float2*)&Wih0[r*32 + 2*p];
        *(float2*)&sW0h[o] = *(const float2*)&Whh0[r*32 + 2*p];
        *(float2*)&sW1i[o] = *(const float2*)&Wih1[r*32 + 2*p];
        *(float2*)&sW1h[o] = *(const float2*)&Whh1[r*32 + 2*p];
    }

    const int k   = tid & 31;
    const int lb  = tid & 32;
    const int seq = blockIdx.x * 4 + (tid >> 5);

    float b0i = bih0[k]    + bhh0[k];
    float b0f = bih0[32+k] + bhh0[32+k];
    float b0g = bih0[64+k] + bhh0[64+k];
    float b0o = bih0[96+k] + bhh0[96+k];
    float b1i = bih1[k]    + bhh1[k];
    float b1f = bih1[32+k] + bhh1[32+k];
    float b1g = bih1[64+k] + bhh1[64+k];
    float b1o = bih1[96+k] + bhh1[96+k];

    __syncthreads();

    float h0 = 0.f, h1 = 0.f, c0 = 0.f, c1 = 0.f;
    const float* xp = hgat + (size_t)seq * 384;

    for (int t = 0; t < 12; t++) {
        float xk = xp[t*32 + k];                      // coalesced per seq
        h0 = lstep(sW0i, sW0h, b0i, b0f, b0g, b0o, xk, h0, c0, k, lb);
        h1 = lstep(sW1i, sW1h, b1i, b1f, b1g, b1o, h0, h1, c1, k, lb);
    }

    // FC: rows r=k (all lanes) and r=32+k (lanes 0..3)
    float acc0 = fcb[k];
    float acc1 = (k < 4) ? fcb[32 + k] : 0.f;
    #pragma unroll
    for (int c = 0; c < 32; c++) {
        float hc = __shfl(h1, lb + c, 64);
        acc0 += fcW[k*32 + c] * hc;
        if (k < 4) acc1 += fcW[(32 + k)*32 + c] * hc;
    }
    out[seq*36 + k] = acc0;
    if (k < 4) out[seq*36 + 32 + k] = acc1;
}

// =================== fallback (round-3 kernel, zero-ws, known-good) ===================
__device__ __forceinline__ void lstm_step_fb(
    const float* __restrict__ sWi, const float* __restrict__ sWh,
    float bzi, float bzf, float bzg, float bzo,
    const float (&xf)[32], float (&hf)[32], float& cst, int k, int lb)
{
    float zi = bzi, zf = bzf, zg = bzg, zo = bzo;
    const int sw = k & 15;
    #pragma unroll
    for (int c2 = 0; c2 < 16; c2++) {
        const int col = 2 * (c2 ^ sw);
        float xa = xf[2*c2], xb = xf[2*c2+1];
        float ha = hf[2*c2], hb = hf[2*c2+1];
        float2 wiA = *(const float2*)&sWi[(0  + k)*32 + col];
        float2 whA = *(const float2*)&sWh[(0  + k)*32 + col];
        zi += wiA.x*xa + wiA.y*xb + whA.x*ha + whA.y*hb;
        float2 wiB = *(const float2*)&sWi[(32 + k)*32 + col];
        float2 whB = *(const float2*)&sWh[(32 + k)*32 + col];
        zf += wiB.x*xa + wiB.y*xb + whB.x*ha + whB.y*hb;
        float2 wiC = *(const float2*)&sWi[(64 + k)*32 + col];
        float2 whC = *(const float2*)&sWh[(64 + k)*32 + col];
        zg += wiC.x*xa + wiC.y*xb + whC.x*ha + whC.y*hb;
        float2 wiD = *(const float2*)&sWi[(96 + k)*32 + col];
        float2 whD = *(const float2*)&sWh[(96 + k)*32 + col];
        zo += wiD.x*xa + wiD.y*xb + whD.x*ha + whD.y*hb;
    }
    float ig = sgm(zi)*tanhf(zg);
    cst = sgm(zf)*cst + ig;
    float hl = sgm(zo)*tanhf(cst);
    #pragma unroll
    for (int d = 0; d < 32; d++) hf[d] = __shfl(hl, lb + d, 64);
}

__global__ __launch_bounds__(256) void k_fused_fb(
    const float* __restrict__ A,    const float* __restrict__ X,
    const float* __restrict__ Wg,   const float* __restrict__ aat,
    const float* __restrict__ Wih0, const float* __restrict__ Whh0,
    const float* __restrict__ bih0, const float* __restrict__ bhh0,
    const float* __restrict__ Wih1, const float* __restrict__ Whh1,
    const float* __restrict__ bih1, const float* __restrict__ bhh1,
    const float* __restrict__ fcW,  const float* __restrict__ fcb,
    float* __restrict__ out)
{
    __shared__ float sW0i[4096], sW0h[4096], sW1i[4096], sW1h[4096];
    const int tid = threadIdx.x;
    for (int x2 = tid; x2 < 2048; x2 += 256) {
        int r = x2 >> 4, p = x2 & 15;
        int o = r*32 + 2*(p ^ (r & 15));
        *(float2*)&sW0i[o] = *(const float2*)&Wih0[r*32 + 2*p];
        *(float2*)&sW0h[o] = *(const float2*)&Whh0[r*32 + 2*p];
        *(float2*)&sW1i[o] = *(const float2*)&Wih1[r*32 + 2*p];
        *(float2*)&sW1h[o] = *(const float2*)&Whh1[r*32 + 2*p];
    }
    const int w   = tid >> 5;
    const int k   = tid & 31;
    const int lb  = tid & 32;
    const int seq = blockIdx.x * 8 + w;
    const int b   = seq / 300, i = seq % 300;

    int nb0 = 0, nb1 = 0, cntv = 0;
    for (int j0 = 0; j0 < 300; j0 += 32) {
        int j = j0 + k;
        bool p = (j < 300) && (A[i*300 + j] != 0.f);
        unsigned long long m64 = __ballot(p);
        unsigned mm = (unsigned)(m64 >> lb);
        while (mm) {
            int bpos = __ffs(mm) - 1;
            if ((cntv & 31) == k && cntv < 64) {
                if (cntv & 32) nb1 = j0 + bpos; else nb0 = j0 + bpos;
            }
            cntv++;
            mm &= mm - 1;
        }
    }
    if (cntv > 64) cntv = 64;

    const int dd = k & 3;
    float wg0 = Wg[k*3+0], wg1 = Wg[k*3+1], wg2 = Wg[k*3+2];
    float alv = aat[dd],   arv = aat[4+dd];
    float b0i = bih0[k]    + bhh0[k];
    float b0f = bih0[32+k] + bhh0[32+k];
    float b0g = bih0[64+k] + bhh0[64+k];
    float b0o = bih0[96+k] + bhh0[96+k];
    float b1i = bih1[k]    + bhh1[k];
    float b1f = bih1[32+k] + bhh1[32+k];
    float b1g = bih1[64+k] + bhh1[64+k];
    float b1o = bih1[96+k] + bhh1[96+k];

    __syncthreads();

    float h0f[32], h1f[32];
    #pragma unroll
    for (int d = 0; d < 32; d++) { h0f[d] = 0.f; h1f[d] = 0.f; }
    float c0 = 0.f, c1 = 0.f;
    const size_t xrow = (size_t)(b*300 + i) * 36;

    for (int t = 0; t < 12; t++) {
        float gi = wg0*X[xrow + t*3 + 0] + wg1*X[xrow + t*3 + 1]
                 + wg2*X[xrow + t*3 + 2];
        float gl = gi * alv;
        gl += __shfl_xor(gl, 1, 64);
        gl += __shfl_xor(gl, 2, 64);

        float m = -1e30f, s = 0.f, acc = 0.f;
        for (int kk = 0; kk < cntv; kk++) {
            int v = (kk & 32) ? nb1 : nb0;
            int j = __shfl(v, lb + (kk & 31), 64);
            size_t xj = (size_t)(b*300 + j) * 36 + t*3;
            float gj = wg0*X[xj+0] + wg1*X[xj+1] + wg2*X[xj+2];
            float gr = gj * arv;
            gr += __shfl_xor(gr, 1, 64);
            gr += __shfl_xor(gr, 2, 64);
            float e = gl + gr;
            e = e > 0.f ? e : 0.2f*e;
            if (e > m) {
                float sc = __expf(m - e);
                s = s*sc + 1.f; acc = acc*sc + gj; m = e;
            } else {
                float wgt = __expf(e - m);
                s += wgt; acc += wgt*gj;
            }
        }
        float x_k = acc / s;
        float xf[32];
        #pragma unroll
        for (int d = 0; d < 32; d++) xf[d] = __shfl(x_k, lb + d, 64);
        lstm_step_fb(sW0i, sW0h, b0i, b0f, b0g, b0o, xf,  h0f, c0, k, lb);
        lstm_step_fb(sW1i, sW1h, b1i, b1f, b1g, b1o, h0f, h1f, c1, k, lb);
    }

    for (int r = k; r < 36; r += 32) {
        float a2 = fcb[r];
        #pragma unroll
        for (int c2 = 0; c2 < 16; c2++) {
            float2 u = *(const float2*)&fcW[r*32 + 2*c2];
            a2 += u.x*h1f[2*c2] + u.y*h1f[2*c2+1];
        }
        out[seq*36 + r] = a2;
    }
}

extern "C" void kernel_launch(void* const* d_in, const int* in_sizes, int n_in,
                              void* d_out, int out_size, void* d_ws, size_t ws_size,
                              hipStream_t stream)
{
    const float* A    = (const float*)d_in[0];
    const float* X    = (const float*)d_in[1];
    const float* Wg   = (const float*)d_in[2];
    const float* aat  = (const float*)d_in[3];
    const float* Wih0 = (const float*)d_in[4];
    const float* Whh0 = (const float*)d_in[5];
    const float* bih0 = (const float*)d_in[6];
    const float* bhh0 = (const float*)d_in[7];
    const float* Wih1 = (const float*)d_in[8];
    const float* Whh1 = (const float*)d_in[9];
    const float* bih1 = (const float*)d_in[10];
    const float* bhh1 = (const float*)d_in[11];
    const float* fcW  = (const float*)d_in[12];
    const float* fcb  = (const float*)d_in[13];
    float* out = (float*)d_out;

    // ws layout: cnt[300] + pad -> idx[300*64] -> hgat[2400*12*32]
    const size_t need = (320 + 300*64) * sizeof(int) + (size_t)2400*12*32*sizeof(float);
    if (ws_size >= need) {
        int*   cnt  = (int*)d_ws;
        int*   idx  = cnt + 320;
        float* hgat = (float*)(idx + 300*64);
        k_nbr <<<300, 64,  0, stream>>>(A, cnt, idx);
        k_attn<<<600, 256, 0, stream>>>(X, Wg, aat, cnt, idx, hgat);
        k_lstm<<<600, 128, 0, stream>>>(hgat, Wih0, Whh0, bih0, bhh0,
                                        Wih1, Whh1, bih1, bhh1, fcW, fcb, out);
    } else {
        k_fused_fb<<<300, 256, 0, stream>>>(A, X, Wg, aat,
                                            Wih0, Whh0, bih0, bhh0,
                                            Wih1, Whh1, bih1, bhh1,
                                            fcW, fcb, out);
    }
}

// Round 5
// 72.615 us; speedup vs baseline: 6.2351x; 3.0174x over previous
//
#include <hip/hip_runtime.h>

__device__ __forceinline__ float sgm(float x) { return 1.f / (1.f + __expf(-x)); }
__device__ __forceinline__ float tanh_fast(float x) {
    float e = __expf(-2.f * fabsf(x));
    float t = (1.f - e) / (1.f + e);
    return copysignf(t, x);
}

// =================== kernel 0: neighbor lists (one wave per row i) ===================
__global__ void k_nbr(const float* __restrict__ A, int* __restrict__ cnt, int* __restrict__ idx)
{
    int i = blockIdx.x;
    int lane = threadIdx.x;
    int c = 0;
    for (int j0 = 0; j0 < 300; j0 += 64) {
        int j = j0 + lane;
        bool p = (j < 300) && (A[i*300 + j] != 0.f);
        unsigned long long m = __ballot(p);
        if (p) {
            int pos = __popcll(m & ((1ull << lane) - 1ull));
            if (c + pos < 64) idx[i*64 + c + pos] = j;
        }
        c += __popcll(m);
    }
    if (c > 64) c = 64;
    if (lane == 0) cnt[i] = c;
}

// =================== kernel 1: GAT attention -> hgat ===================
__global__ __launch_bounds__(256, 4) void k_attn(
    const float* __restrict__ X, const float* __restrict__ Wg,
    const float* __restrict__ aat, const int* __restrict__ cnt,
    const int* __restrict__ idx, float* __restrict__ hgat)
{
    int seq = blockIdx.x * 4 + (threadIdx.x >> 6);   // 0..2399
    int lane = threadIdx.x & 63;
    int h = lane >> 3, j8 = lane & 7, d = j8 & 3;
    int b = seq / 300, i = seq % 300;

    float wal0=0.f, wal1=0.f, wal2=0.f, war0=0.f, war1=0.f, war2=0.f;
    #pragma unroll
    for (int dd = 0; dd < 4; dd++) {
        float av = aat[dd], bv = aat[4+dd];
        const float* wr = Wg + (h*4+dd)*3;
        wal0 += wr[0]*av; wal1 += wr[1]*av; wal2 += wr[2]*av;
        war0 += wr[0]*bv; war1 += wr[1]*bv; war2 += wr[2]*bv;
    }
    const float* wp = Wg + (h*4+d)*3;
    float wp0 = wp[0], wp1 = wp[1], wp2 = wp[2];

    int c = cnt[i];
    int jj[8];
    #pragma unroll
    for (int q = 0; q < 8; q++) jj[q] = idx[i*64 + q*8 + j8];

    const float* Xi = X + (size_t)(b*300 + i) * 36;

    for (int t = 0; t < 12; t++) {
        float x0 = Xi[t*3+0], x1 = Xi[t*3+1], x2 = Xi[t*3+2];
        float gl = x0*wal0 + x1*wal1 + x2*wal2;

        float m = -1e30f, s = 0.f, a0 = 0.f, a1 = 0.f, a2 = 0.f;
        for (int q = 0; q*8 + j8 < c; q++) {
            int j = jj[q];
            const float* Xj = X + (size_t)(b*300 + j) * 36 + t*3;
            float y0 = Xj[0], y1 = Xj[1], y2 = Xj[2];
            float gr = y0*war0 + y1*war1 + y2*war2;
            float e = gl + gr;
            e = e > 0.f ? e : 0.2f*e;
            if (e > m) {
                float sc = __expf(m - e);
                s = s*sc + 1.f;
                a0 = a0*sc + y0; a1 = a1*sc + y1; a2 = a2*sc + y2;
                m = e;
            } else {
                float w = __expf(e - m);
                s += w;
                a0 += w*y0; a1 += w*y1; a2 += w*y2;
            }
        }
        #pragma unroll
        for (int off = 1; off <= 4; off <<= 1) {
            float m2 = __shfl_xor(m, off, 64);
            float s2 = __shfl_xor(s, off, 64);
            float b0 = __shfl_xor(a0, off, 64);
            float b1 = __shfl_xor(a1, off, 64);
            float b2 = __shfl_xor(a2, off, 64);
            float mo = fmaxf(m, m2);
            float w1 = __expf(m - mo), w2 = __expf(m2 - mo);
            s = s*w1 + s2*w2;
            a0 = a0*w1 + b0*w2; a1 = a1*w1 + b1*w2; a2 = a2*w1 + b2*w2;
            m = mo;
        }
        if (j8 < 4) {
            float o = (a0*wp0 + a1*wp1 + a2*wp2) / s;
            hgat[(size_t)(seq*12 + t)*32 + h*4 + d] = o;
        }
    }
}

// =================== kernel 2: LSTM x2 + FC, weights in registers ===================
// Block = 256 thr = 4 waves; wave w owns gate w (z-rows w*32..w*32+31), both layers.
// Lane l: l32 = l&31 -> row w*32+l32; half = l>>5: half 0 = Wih half-row (+bias),
// half 1 = Whh half-row. 64 weight VGPRs/lane; zero weight traffic in the loop.
// x/h broadcast via tiny LDS sbuf (uniform float4 reads = free broadcast).
// Wave 0 does cell updates (c-state in regs) and stages x for t+1. 2 seqs/block.
__global__ __launch_bounds__(256, 4) void k_lstm2(
    const float* __restrict__ hgat,
    const float* __restrict__ Wih0, const float* __restrict__ Whh0,
    const float* __restrict__ bih0, const float* __restrict__ bhh0,
    const float* __restrict__ Wih1, const float* __restrict__ Whh1,
    const float* __restrict__ bih1, const float* __restrict__ bhh1,
    const float* __restrict__ fcW,  const float* __restrict__ fcb,
    float* __restrict__ out)
{
    __shared__ float sbuf[3][2][32];   // [0]=x, [1]=h0, [2]=h1 ; per seq-slot
    __shared__ float zbuf[2][128];

    const int tid  = threadIdx.x;
    const int w    = tid >> 6;         // gate index / wave
    const int l    = tid & 63;
    const int l32  = l & 31;
    const int half = l >> 5;           // 0: Wih part, 1: Whh part
    const int row  = w*32 + l32;       // z-row

    // ---- load this lane's weight half-rows (held in VGPRs for the whole kernel) ----
    const float* W0 = half ? Whh0 : Wih0;
    const float* W1 = half ? Whh1 : Wih1;
    float wr0[32], wr1[32];
    #pragma unroll
    for (int c4 = 0; c4 < 8; c4++) {
        float4 a = *(const float4*)&W0[row*32 + 4*c4];
        wr0[4*c4+0]=a.x; wr0[4*c4+1]=a.y; wr0[4*c4+2]=a.z; wr0[4*c4+3]=a.w;
        float4 b = *(const float4*)&W1[row*32 + 4*c4];
        wr1[4*c4+0]=b.x; wr1[4*c4+1]=b.y; wr1[4*c4+2]=b.z; wr1[4*c4+3]=b.w;
    }
    const float bz0 = (half == 0) ? (bih0[row] + bhh0[row]) : 0.f;
    const float bz1 = (half == 0) ? (bih1[row] + bhh1[row]) : 0.f;

    // update-wave lane mapping
    const int s_up  = l >> 5;          // seq slot (wave 0 only)
    const int k_up  = l & 31;          // cell
    const int seq_up = blockIdx.x*2 + s_up;

    if (w == 0) {
        sbuf[1][s_up][k_up] = 0.f;
        sbuf[2][s_up][k_up] = 0.f;
        sbuf[0][s_up][k_up] = hgat[(size_t)seq_up*384 + k_up];   // t = 0
    }
    __syncthreads();

    float c0 = 0.f, c1 = 0.f;          // cell states (wave 0's lanes)

    for (int t = 0; t < 12; t++) {
        // ---- layer 0 z: half 0 reads x-buf, half 1 reads h0-buf ----
        {
            const float* dp = &sbuf[half][0][0];
            float a0 = bz0, a1 = bz0;
            #pragma unroll
            for (int c4 = 0; c4 < 8; c4++) {
                float4 d0 = *(const float4*)&dp[ 0 + 4*c4];
                float4 d1 = *(const float4*)&dp[32 + 4*c4];
                a0 += wr0[4*c4+0]*d0.x + wr0[4*c4+1]*d0.y + wr0[4*c4+2]*d0.z + wr0[4*c4+3]*d0.w;
                a1 += wr0[4*c4+0]*d1.x + wr0[4*c4+1]*d1.y + wr0[4*c4+2]*d1.z + wr0[4*c4+3]*d1.w;
            }
            a0 += __shfl_xor(a0, 32, 64);
            a1 += __shfl_xor(a1, 32, 64);
            if (half == 0) { zbuf[0][row] = a0; zbuf[1][row] = a1; }
        }
        __syncthreads();
        if (w == 0) {
            float zi = zbuf[s_up][k_up],      zf = zbuf[s_up][32+k_up];
            float zg = zbuf[s_up][64+k_up],   zo = zbuf[s_up][96+k_up];
            c0 = sgm(zf)*c0 + sgm(zi)*tanh_fast(zg);
            sbuf[1][s_up][k_up] = sgm(zo)*tanh_fast(c0);
            if (t + 1 < 12)                       // stage next x (x-buf free now)
                sbuf[0][s_up][k_up] = hgat[(size_t)seq_up*384 + (t+1)*32 + k_up];
        }
        __syncthreads();
        // ---- layer 1 z: half 0 reads h0-buf, half 1 reads h1-buf ----
        {
            const float* dp = &sbuf[1 + half][0][0];
            float a0 = bz1, a1 = bz1;
            #pragma unroll
            for (int c4 = 0; c4 < 8; c4++) {
                float4 d0 = *(const float4*)&dp[ 0 + 4*c4];
                float4 d1 = *(const float4*)&dp[32 + 4*c4];
                a0 += wr1[4*c4+0]*d0.x + wr1[4*c4+1]*d0.y + wr1[4*c4+2]*d0.z + wr1[4*c4+3]*d0.w;
                a1 += wr1[4*c4+0]*d1.x + wr1[4*c4+1]*d1.y + wr1[4*c4+2]*d1.z + wr1[4*c4+3]*d1.w;
            }
            a0 += __shfl_xor(a0, 32, 64);
            a1 += __shfl_xor(a1, 32, 64);
            if (half == 0) { zbuf[0][row] = a0; zbuf[1][row] = a1; }
        }
        __syncthreads();
        if (w == 0) {
            float zi = zbuf[s_up][k_up],      zf = zbuf[s_up][32+k_up];
            float zg = zbuf[s_up][64+k_up],   zo = zbuf[s_up][96+k_up];
            c1 = sgm(zf)*c1 + sgm(zi)*tanh_fast(zg);
            sbuf[2][s_up][k_up] = sgm(zo)*tanh_fast(c1);
        }
        __syncthreads();
    }

    // ---- FC: 72 outputs (2 seqs x 36) ----
    if (tid < 72) {
        int s = tid / 36, r = tid % 36;
        float acc = fcb[r];
        #pragma unroll
        for (int c4 = 0; c4 < 8; c4++) {
            float4 u = *(const float4*)&fcW[r*32 + 4*c4];
            acc += u.x*sbuf[2][s][4*c4+0] + u.y*sbuf[2][s][4*c4+1]
                 + u.z*sbuf[2][s][4*c4+2] + u.w*sbuf[2][s][4*c4+3];
        }
        out[(blockIdx.x*2 + s)*36 + r] = acc;
    }
}

// =================== fallback (round-3 kernel, zero-ws, known-good) ===================
__device__ __forceinline__ void lstm_step_fb(
    const float* __restrict__ sWi, const float* __restrict__ sWh,
    float bzi, float bzf, float bzg, float bzo,
    const float (&xf)[32], float (&hf)[32], float& cst, int k, int lb)
{
    float zi = bzi, zf = bzf, zg = bzg, zo = bzo;
    const int sw = k & 15;
    #pragma unroll
    for (int c2 = 0; c2 < 16; c2++) {
        const int col = 2 * (c2 ^ sw);
        float xa = xf[2*c2], xb = xf[2*c2+1];
        float ha = hf[2*c2], hb = hf[2*c2+1];
        float2 wiA = *(const float2*)&sWi[(0  + k)*32 + col];
        float2 whA = *(const float2*)&sWh[(0  + k)*32 + col];
        zi += wiA.x*xa + wiA.y*xb + whA.x*ha + whA.y*hb;
        float2 wiB = *(const float2*)&sWi[(32 + k)*32 + col];
        float2 whB = *(const float2*)&sWh[(32 + k)*32 + col];
        zf += wiB.x*xa + wiB.y*xb + whB.x*ha + whB.y*hb;
        float2 wiC = *(const float2*)&sWi[(64 + k)*32 + col];
        float2 whC = *(const float2*)&sWh[(64 + k)*32 + col];
        zg += wiC.x*xa + wiC.y*xb + whC.x*ha + whC.y*hb;
        float2 wiD = *(const float2*)&sWi[(96 + k)*32 + col];
        float2 whD = *(const float2*)&sWh[(96 + k)*32 + col];
        zo += wiD.x*xa + wiD.y*xb + whD.x*ha + whD.y*hb;
    }
    float ig = sgm(zi)*tanhf(zg);
    cst = sgm(zf)*cst + ig;
    float hl = sgm(zo)*tanhf(cst);
    #pragma unroll
    for (int d = 0; d < 32; d++) hf[d] = __shfl(hl, lb + d, 64);
}

__global__ __launch_bounds__(256) void k_fused_fb(
    const float* __restrict__ A,    const float* __restrict__ X,
    const float* __restrict__ Wg,   const float* __restrict__ aat,
    const float* __restrict__ Wih0, const float* __restrict__ Whh0,
    const float* __restrict__ bih0, const float* __restrict__ bhh0,
    const float* __restrict__ Wih1, const float* __restrict__ Whh1,
    const float* __restrict__ bih1, const float* __restrict__ bhh1,
    const float* __restrict__ fcW,  const float* __restrict__ fcb,
    float* __restrict__ out)
{
    __shared__ float sW0i[4096], sW0h[4096], sW1i[4096], sW1h[4096];
    const int tid = threadIdx.x;
    for (int x2 = tid; x2 < 2048; x2 += 256) {
        int r = x2 >> 4, p = x2 & 15;
        int o = r*32 + 2*(p ^ (r & 15));
        *(float2*)&sW0i[o] = *(const float2*)&Wih0[r*32 + 2*p];
        *(float2*)&sW0h[o] = *(const float2*)&Whh0[r*32 + 2*p];
        *(float2*)&sW1i[o] = *(const float2*)&Wih1[r*32 + 2*p];
        *(float2*)&sW1h[o] = *(const float2*)&Whh1[r*32 + 2*p];
    }
    const int w   = tid >> 5;
    const int k   = tid & 31;
    const int lb  = tid & 32;
    const int seq = blockIdx.x * 8 + w;
    const int b   = seq / 300, i = seq % 300;

    int nb0 = 0, nb1 = 0, cntv = 0;
    for (int j0 = 0; j0 < 300; j0 += 32) {
        int j = j0 + k;
        bool p = (j < 300) && (A[i*300 + j] != 0.f);
        unsigned long long m64 = __ballot(p);
        unsigned mm = (unsigned)(m64 >> lb);
        while (mm) {
            int bpos = __ffs(mm) - 1;
            if ((cntv & 31) == k && cntv < 64) {
                if (cntv & 32) nb1 = j0 + bpos; else nb0 = j0 + bpos;
            }
            cntv++;
            mm &= mm - 1;
        }
    }
    if (cntv > 64) cntv = 64;

    const int dd = k & 3;
    float wg0 = Wg[k*3+0], wg1 = Wg[k*3+1], wg2 = Wg[k*3+2];
    float alv = aat[dd],   arv = aat[4+dd];
    float b0i = bih0[k]    + bhh0[k];
    float b0f = bih0[32+k] + bhh0[32+k];
    float b0g = bih0[64+k] + bhh0[64+k];
    float b0o = bih0[96+k] + bhh0[96+k];
    float b1i = bih1[k]    + bhh1[k];
    float b1f = bih1[32+k] + bhh1[32+k];
    float b1g = bih1[64+k] + bhh1[64+k];
    float b1o = bih1[96+k] + bhh1[96+k];

    __syncthreads();

    float h0f[32], h1f[32];
    #pragma unroll
    for (int d = 0; d < 32; d++) { h0f[d] = 0.f; h1f[d] = 0.f; }
    float c0 = 0.f, c1 = 0.f;
    const size_t xrow = (size_t)(b*300 + i) * 36;

    for (int t = 0; t < 12; t++) {
        float gi = wg0*X[xrow + t*3 + 0] + wg1*X[xrow + t*3 + 1]
                 + wg2*X[xrow + t*3 + 2];
        float gl = gi * alv;
        gl += __shfl_xor(gl, 1, 64);
        gl += __shfl_xor(gl, 2, 64);

        float m = -1e30f, s = 0.f, acc = 0.f;
        for (int kk = 0; kk < cntv; kk++) {
            int v = (kk & 32) ? nb1 : nb0;
            int j = __shfl(v, lb + (kk & 31), 64);
            size_t xj = (size_t)(b*300 + j) * 36 + t*3;
            float gj = wg0*X[xj+0] + wg1*X[xj+1] + wg2*X[xj+2];
            float gr = gj * arv;
            gr += __shfl_xor(gr, 1, 64);
            gr += __shfl_xor(gr, 2, 64);
            float e = gl + gr;
            e = e > 0.f ? e : 0.2f*e;
            if (e > m) {
                float sc = __expf(m - e);
                s = s*sc + 1.f; acc = acc*sc + gj; m = e;
            } else {
                float wgt = __expf(e - m);
                s += wgt; acc += wgt*gj;
            }
        }
        float x_k = acc / s;
        float xf[32];
        #pragma unroll
        for (int d = 0; d < 32; d++) xf[d] = __shfl(x_k, lb + d, 64);
        lstm_step_fb(sW0i, sW0h, b0i, b0f, b0g, b0o, xf,  h0f, c0, k, lb);
        lstm_step_fb(sW1i, sW1h, b1i, b1f, b1g, b1o, h0f, h1f, c1, k, lb);
    }

    for (int r = k; r < 36; r += 32) {
        float a2 = fcb[r];
        #pragma unroll
        for (int c2 = 0; c2 < 16; c2++) {
            float2 u = *(const float2*)&fcW[r*32 + 2*c2];
            a2 += u.x*h1f[2*c2] + u.y*h1f[2*c2+1];
        }
        out[seq*36 + r] = a2;
    }
}

extern "C" void kernel_launch(void* const* d_in, const int* in_sizes, int n_in,
                              void* d_out, int out_size, void* d_ws, size_t ws_size,
                              hipStream_t stream)
{
    const float* A    = (const float*)d_in[0];
    const float* X    = (const float*)d_in[1];
    const float* Wg   = (const float*)d_in[2];
    const float* aat  = (const float*)d_in[3];
    const float* Wih0 = (const float*)d_in[4];
    const float* Whh0 = (const float*)d_in[5];
    const float* bih0 = (const float*)d_in[6];
    const float* bhh0 = (const float*)d_in[7];
    const float* Wih1 = (const float*)d_in[8];
    const float* Whh1 = (const float*)d_in[9];
    const float* bih1 = (const float*)d_in[10];
    const float* bhh1 = (const float*)d_in[11];
    const float* fcW  = (const float*)d_in[12];
    const float* fcb  = (const float*)d_in[13];
    float* out = (float*)d_out;

    // ws layout: cnt[300] + pad -> idx[300*64] -> hgat[2400*12*32]
    const size_t need = (320 + 300*64) * sizeof(int) + (size_t)2400*12*32*sizeof(float);
    if (ws_size >= need) {
        int*   cnt  = (int*)d_ws;
        int*   idx  = cnt + 320;
        float* hgat = (float*)(idx + 300*64);
        k_nbr  <<<300,  64,  0, stream>>>(A, cnt, idx);
        k_attn <<<600,  256, 0, stream>>>(X, Wg, aat, cnt, idx, hgat);
        k_lstm2<<<1200, 256, 0, stream>>>(hgat, Wih0, Whh0, bih0, bhh0,
                                          Wih1, Whh1, bih1, bhh1, fcW, fcb, out);
    } else {
        k_fused_fb<<<300, 256, 0, stream>>>(A, X, Wg, aat,
                                            Wih0, Whh0, bih0, bhh0,
                                            Wih1, Whh1, bih1, bhh1,
                                            fcW, fcb, out);
    }
}

// Round 6
// 52.855 us; speedup vs baseline: 8.5661x; 1.3739x over previous
//
#include <hip/hip_runtime.h>

typedef __attribute__((ext_vector_type(8))) short s8v;   // 8 x bf16 (bit pattern)
typedef __attribute__((ext_vector_type(4))) float f4v;

__device__ __forceinline__ float sgm(float x) { return 1.f / (1.f + __expf(-x)); }
__device__ __forceinline__ float tanh_fast(float x) {
    float e = __expf(-2.f * fabsf(x));
    float t = (1.f - e) / (1.f + e);
    return copysignf(t, x);
}
// split f32 -> bf16 hi + bf16 lo (x ~= hi + lo, residual ~2^-17 |x|)
__device__ __forceinline__ void bsplit(float x, short& hi, short& lo) {
    unsigned u = __float_as_uint(x);
    unsigned hb = u & 0xffff0000u;
    hi = (short)(hb >> 16);
    float r = x - __uint_as_float(hb);
    lo = (short)(__float_as_uint(r) >> 16);
}

// =================== kernel 0: neighbor lists (one wave per row i) ===================
__global__ void k_nbr(const float* __restrict__ A, int* __restrict__ cnt, int* __restrict__ idx)
{
    int i = blockIdx.x;
    int lane = threadIdx.x;
    int c = 0;
    for (int j0 = 0; j0 < 300; j0 += 64) {
        int j = j0 + lane;
        bool p = (j < 300) && (A[i*300 + j] != 0.f);
        unsigned long long m = __ballot(p);
        if (p) {
            int pos = __popcll(m & ((1ull << lane) - 1ull));
            if (c + pos < 64) idx[i*64 + c + pos] = j;
        }
        c += __popcll(m);
    }
    if (c > 64) c = 64;
    if (lane == 0) cnt[i] = c;
}

// =================== kernel 1: GAT attention -> hgat ===================
__global__ __launch_bounds__(256, 4) void k_attn(
    const float* __restrict__ X, const float* __restrict__ Wg,
    const float* __restrict__ aat, const int* __restrict__ cnt,
    const int* __restrict__ idx, float* __restrict__ hgat)
{
    int seq = blockIdx.x * 4 + (threadIdx.x >> 6);   // 0..2399
    int lane = threadIdx.x & 63;
    int h = lane >> 3, j8 = lane & 7, d = j8 & 3;
    int b = seq / 300, i = seq % 300;

    float wal0=0.f, wal1=0.f, wal2=0.f, war0=0.f, war1=0.f, war2=0.f;
    #pragma unroll
    for (int dd = 0; dd < 4; dd++) {
        float av = aat[dd], bv = aat[4+dd];
        const float* wr = Wg + (h*4+dd)*3;
        wal0 += wr[0]*av; wal1 += wr[1]*av; wal2 += wr[2]*av;
        war0 += wr[0]*bv; war1 += wr[1]*bv; war2 += wr[2]*bv;
    }
    const float* wp = Wg + (h*4+d)*3;
    float wp0 = wp[0], wp1 = wp[1], wp2 = wp[2];

    int c = cnt[i];
    int jj[8];
    #pragma unroll
    for (int q = 0; q < 8; q++) jj[q] = idx[i*64 + q*8 + j8];

    const float* Xi = X + (size_t)(b*300 + i) * 36;

    for (int t = 0; t < 12; t++) {
        float x0 = Xi[t*3+0], x1 = Xi[t*3+1], x2 = Xi[t*3+2];
        float gl = x0*wal0 + x1*wal1 + x2*wal2;

        float m = -1e30f, s = 0.f, a0 = 0.f, a1 = 0.f, a2 = 0.f;
        for (int q = 0; q*8 + j8 < c; q++) {
            int j = jj[q];
            const float* Xj = X + (size_t)(b*300 + j) * 36 + t*3;
            float y0 = Xj[0], y1 = Xj[1], y2 = Xj[2];
            float gr = y0*war0 + y1*war1 + y2*war2;
            float e = gl + gr;
            e = e > 0.f ? e : 0.2f*e;
            if (e > m) {
                float sc = __expf(m - e);
                s = s*sc + 1.f;
                a0 = a0*sc + y0; a1 = a1*sc + y1; a2 = a2*sc + y2;
                m = e;
            } else {
                float w = __expf(e - m);
                s += w;
                a0 += w*y0; a1 += w*y1; a2 += w*y2;
            }
        }
        #pragma unroll
        for (int off = 1; off <= 4; off <<= 1) {
            float m2 = __shfl_xor(m, off, 64);
            float s2 = __shfl_xor(s, off, 64);
            float b0 = __shfl_xor(a0, off, 64);
            float b1 = __shfl_xor(a1, off, 64);
            float b2 = __shfl_xor(a2, off, 64);
            float mo = fmaxf(m, m2);
            float w1 = __expf(m - mo), w2 = __expf(m2 - mo);
            s = s*w1 + s2*w2;
            a0 = a0*w1 + b0*w2; a1 = a1*w1 + b1*w2; a2 = a2*w1 + b2*w2;
            m = mo;
        }
        if (j8 < 4) {
            float o = (a0*wp0 + a1*wp1 + a2*wp2) / s;
            hgat[(size_t)(seq*12 + t)*32 + h*4 + d] = o;
        }
    }
}

// =================== kernel 2: LSTM x2 + FC via MFMA, bf16 hi/lo split ===================
// 240 blocks x 512 thr (8 waves), 10 seqs/block (N padded to 16).
// z(128 x 16) = W(128 x 64) @ v(64 x 16) per layer-step; wave w owns z-rows w*16..w*16+15.
// A-frag (W rows, hi/lo) in VGPRs all kernel. v in LDS as [seq][72] bf16 rows (hi & lo arrays).
// Per wave per layer-step: 4 ds_read_b128 + 6 MFMA + 1 ds_write_b128.  Update phase:
// 320 threads = (seq, cell), c-state in regs, writes h back as bf16 hi/lo.
#define SQ 10

__global__ __launch_bounds__(512, 1) void k_lstm4(
    const float* __restrict__ hgat,
    const float* __restrict__ Wih0, const float* __restrict__ Whh0,
    const float* __restrict__ bih0, const float* __restrict__ bhh0,
    const float* __restrict__ Wih1, const float* __restrict__ Whh1,
    const float* __restrict__ bih1, const float* __restrict__ bhh1,
    const float* __restrict__ fcW,  const float* __restrict__ fcb,
    float* __restrict__ out)
{
    __shared__ __align__(16) short vh0[16*72], vl0[16*72];   // layer0 input [x ; h0]
    __shared__ __align__(16) short vh1[16*72], vl1[16*72];   // layer1 input [h0 ; h1]
    __shared__ __align__(16) float zb[16*132];               // z  [seq][row], stride 132
    __shared__ float sh1f[SQ*32];                            // final h1 (f32) for FC

    const int tid = threadIdx.x;
    const int w   = tid >> 6;        // wave 0..7
    const int l   = tid & 63;
    const int n16 = l & 15;          // A: m within tile ; B/D: n (seq)
    const int g   = l >> 4;          // k-group 0..3
    const int zrow = w*16 + n16;     // this lane's A row (z-row)

    // ---- A fragments: W rows split hi/lo; kt=0 <- Wih (k 0..31), kt=1 <- Whh ----
    s8v a0h[2], a0l[2], a1h[2], a1l[2];
    {
        const float* s00 = Wih0 + zrow*32 + g*8;
        const float* s01 = Whh0 + zrow*32 + g*8;
        const float* s10 = Wih1 + zrow*32 + g*8;
        const float* s11 = Whh1 + zrow*32 + g*8;
        #pragma unroll
        for (int j = 0; j < 8; j++) {
            short hh, ll;
            bsplit(s00[j], hh, ll); a0h[0][j]=hh; a0l[0][j]=ll;
            bsplit(s01[j], hh, ll); a0h[1][j]=hh; a0l[1][j]=ll;
            bsplit(s10[j], hh, ll); a1h[0][j]=hh; a1l[0][j]=ll;
            bsplit(s11[j], hh, ll); a1h[1][j]=hh; a1l[1][j]=ll;
        }
    }
    // bias fragment in D layout: row = w*16 + g*4 + r, col = seq (same for all cols)
    f4v bias0, bias1;
    #pragma unroll
    for (int r = 0; r < 4; r++) {
        int rr = w*16 + g*4 + r;
        bias0[r] = bih0[rr] + bhh0[rr];
        bias1[r] = bih1[rr] + bhh1[rr];
    }

    const int us = tid >> 5, uc = tid & 31;   // update mapping: seq, cell
    const bool upd = tid < SQ*32;
    const int seq0 = blockIdx.x * SQ;

    if (upd) {
        short hh, ll;
        bsplit(hgat[(size_t)(seq0+us)*384 + uc], hh, ll);   // x at t=0
        vh0[us*72 + uc] = hh;      vl0[us*72 + uc] = ll;
        vh0[us*72 + 32 + uc] = 0;  vl0[us*72 + 32 + uc] = 0;   // h0 = 0
        vh1[us*72 + uc] = 0;       vl1[us*72 + uc] = 0;        // h0 = 0
        vh1[us*72 + 32 + uc] = 0;  vl1[us*72 + 32 + uc] = 0;   // h1 = 0
    }
    __syncthreads();

    float c0 = 0.f, c1 = 0.f;
    const int boff = n16 * 144;    // byte offset of this lane's seq row in v arrays

    for (int t = 0; t < 12; t++) {
        // ===== layer 0: z = b + W0 @ [x ; h0]  (Wh*vh + Wl*vh + Wh*vl) =====
        {
            s8v bh0 = *(const s8v*)((const char*)vh0 + boff +      g*16);
            s8v bh1 = *(const s8v*)((const char*)vh0 + boff + 64 + g*16);
            s8v bl0 = *(const s8v*)((const char*)vl0 + boff +      g*16);
            s8v bl1 = *(const s8v*)((const char*)vl0 + boff + 64 + g*16);
            f4v acc = bias0;
            acc = __builtin_amdgcn_mfma_f32_16x16x32_bf16(a0h[0], bh0, acc, 0, 0, 0);
            acc = __builtin_amdgcn_mfma_f32_16x16x32_bf16(a0h[1], bh1, acc, 0, 0, 0);
            acc = __builtin_amdgcn_mfma_f32_16x16x32_bf16(a0l[0], bh0, acc, 0, 0, 0);
            acc = __builtin_amdgcn_mfma_f32_16x16x32_bf16(a0l[1], bh1, acc, 0, 0, 0);
            acc = __builtin_amdgcn_mfma_f32_16x16x32_bf16(a0h[0], bl0, acc, 0, 0, 0);
            acc = __builtin_amdgcn_mfma_f32_16x16x32_bf16(a0h[1], bl1, acc, 0, 0, 0);
            *(f4v*)&zb[n16*132 + w*16 + g*4] = acc;   // D: row = w*16+g*4+r, col = n16
        }
        __syncthreads();
        if (upd) {
            float zi = zb[us*132 + uc],      zf = zb[us*132 + 32 + uc];
            float zg = zb[us*132 + 64 + uc], zo = zb[us*132 + 96 + uc];
            c0 = sgm(zf)*c0 + sgm(zi)*tanh_fast(zg);
            float h0v = sgm(zo)*tanh_fast(c0);
            short hh, ll;
            bsplit(h0v, hh, ll);
            vh0[us*72 + 32 + uc] = hh;  vl0[us*72 + 32 + uc] = ll;   // h0 into layer0 v
            vh1[us*72 + uc]      = hh;  vl1[us*72 + uc]      = ll;   // h0 into layer1 v
            if (t + 1 < 12) {            // stage next x (x slot free: layer0 z done)
                bsplit(hgat[(size_t)(seq0+us)*384 + (t+1)*32 + uc], hh, ll);
                vh0[us*72 + uc] = hh; vl0[us*72 + uc] = ll;
            }
        }
        __syncthreads();
        // ===== layer 1: z = b + W1 @ [h0 ; h1] =====
        {
            s8v bh0 = *(const s8v*)((const char*)vh1 + boff +      g*16);
            s8v bh1 = *(const s8v*)((const char*)vh1 + boff + 64 + g*16);
            s8v bl0 = *(const s8v*)((const char*)vl1 + boff +      g*16);
            s8v bl1 = *(const s8v*)((const char*)vl1 + boff + 64 + g*16);
            f4v acc = bias1;
            acc = __builtin_amdgcn_mfma_f32_16x16x32_bf16(a1h[0], bh0, acc, 0, 0, 0);
            acc = __builtin_amdgcn_mfma_f32_16x16x32_bf16(a1h[1], bh1, acc, 0, 0, 0);
            acc = __builtin_amdgcn_mfma_f32_16x16x32_bf16(a1l[0], bh0, acc, 0, 0, 0);
            acc = __builtin_amdgcn_mfma_f32_16x16x32_bf16(a1l[1], bh1, acc, 0, 0, 0);
            acc = __builtin_amdgcn_mfma_f32_16x16x32_bf16(a1h[0], bl0, acc, 0, 0, 0);
            acc = __builtin_amdgcn_mfma_f32_16x16x32_bf16(a1h[1], bl1, acc, 0, 0, 0);
            *(f4v*)&zb[n16*132 + w*16 + g*4] = acc;
        }
        __syncthreads();
        if (upd) {
            float zi = zb[us*132 + uc],      zf = zb[us*132 + 32 + uc];
            float zg = zb[us*132 + 64 + uc], zo = zb[us*132 + 96 + uc];
            c1 = sgm(zf)*c1 + sgm(zi)*tanh_fast(zg);
            float h1v = sgm(zo)*tanh_fast(c1);
            short hh, ll;
            bsplit(h1v, hh, ll);
            vh1[us*72 + 32 + uc] = hh;  vl1[us*72 + 32 + uc] = ll;
            if (t == 11) sh1f[us*32 + uc] = h1v;
        }
        __syncthreads();
    }

    // ---- FC: 360 outputs (10 seqs x 36) ----
    if (tid < SQ*36) {
        int s = tid / 36, r = tid - s*36;
        float acc = fcb[r];
        #pragma unroll
        for (int c4 = 0; c4 < 8; c4++) {
            float4 u = *(const float4*)&fcW[r*32 + 4*c4];
            acc += u.x*sh1f[s*32+4*c4+0] + u.y*sh1f[s*32+4*c4+1]
                 + u.z*sh1f[s*32+4*c4+2] + u.w*sh1f[s*32+4*c4+3];
        }
        out[(seq0 + s)*36 + r] = acc;
    }
}

// =================== fallback (round-3 fused kernel, zero-ws, known-good) ===================
__device__ __forceinline__ void lstm_step_fb(
    const float* __restrict__ sWi, const float* __restrict__ sWh,
    float bzi, float bzf, float bzg, float bzo,
    const float (&xf)[32], float (&hf)[32], float& cst, int k, int lb)
{
    float zi = bzi, zf = bzf, zg = bzg, zo = bzo;
    const int sw = k & 15;
    #pragma unroll
    for (int c2 = 0; c2 < 16; c2++) {
        const int col = 2 * (c2 ^ sw);
        float xa = xf[2*c2], xb = xf[2*c2+1];
        float ha = hf[2*c2], hb = hf[2*c2+1];
        float2 wiA = *(const float2*)&sWi[(0  + k)*32 + col];
        float2 whA = *(const float2*)&sWh[(0  + k)*32 + col];
        zi += wiA.x*xa + wiA.y*xb + whA.x*ha + whA.y*hb;
        float2 wiB = *(const float2*)&sWi[(32 + k)*32 + col];
        float2 whB = *(const float2*)&sWh[(32 + k)*32 + col];
        zf += wiB.x*xa + wiB.y*xb + whB.x*ha + whB.y*hb;
        float2 wiC = *(const float2*)&sWi[(64 + k)*32 + col];
        float2 whC = *(const float2*)&sWh[(64 + k)*32 + col];
        zg += wiC.x*xa + wiC.y*xb + whC.x*ha + whC.y*hb;
        float2 wiD = *(const float2*)&sWi[(96 + k)*32 + col];
        float2 whD = *(const float2*)&sWh[(96 + k)*32 + col];
        zo += wiD.x*xa + wiD.y*xb + whD.x*ha + whD.y*hb;
    }
    float ig = sgm(zi)*tanhf(zg);
    cst = sgm(zf)*cst + ig;
    float hl = sgm(zo)*tanhf(cst);
    #pragma unroll
    for (int d = 0; d < 32; d++) hf[d] = __shfl(hl, lb + d, 64);
}

__global__ __launch_bounds__(256) void k_fused_fb(
    const float* __restrict__ A,    const float* __restrict__ X,
    const float* __restrict__ Wg,   const float* __restrict__ aat,
    const float* __restrict__ Wih0, const float* __restrict__ Whh0,
    const float* __restrict__ bih0, const float* __restrict__ bhh0,
    const float* __restrict__ Wih1, const float* __restrict__ Whh1,
    const float* __restrict__ bih1, const float* __restrict__ bhh1,
    const float* __restrict__ fcW,  const float* __restrict__ fcb,
    float* __restrict__ out)
{
    __shared__ float sW0i[4096], sW0h[4096], sW1i[4096], sW1h[4096];
    const int tid = threadIdx.x;
    for (int x2 = tid; x2 < 2048; x2 += 256) {
        int r = x2 >> 4, p = x2 & 15;
        int o = r*32 + 2*(p ^ (r & 15));
        *(float2*)&sW0i[o] = *(const float2*)&Wih0[r*32 + 2*p];
        *(float2*)&sW0h[o] = *(const float2*)&Whh0[r*32 + 2*p];
        *(float2*)&sW1i[o] = *(const float2*)&Wih1[r*32 + 2*p];
        *(float2*)&sW1h[o] = *(const float2*)&Whh1[r*32 + 2*p];
    }
    const int w   = tid >> 5;
    const int k   = tid & 31;
    const int lb  = tid & 32;
    const int seq = blockIdx.x * 8 + w;
    const int b   = seq / 300, i = seq % 300;

    int nb0 = 0, nb1 = 0, cntv = 0;
    for (int j0 = 0; j0 < 300; j0 += 32) {
        int j = j0 + k;
        bool p = (j < 300) && (A[i*300 + j] != 0.f);
        unsigned long long m64 = __ballot(p);
        unsigned mm = (unsigned)(m64 >> lb);
        while (mm) {
            int bpos = __ffs(mm) - 1;
            if ((cntv & 31) == k && cntv < 64) {
                if (cntv & 32) nb1 = j0 + bpos; else nb0 = j0 + bpos;
            }
            cntv++;
            mm &= mm - 1;
        }
    }
    if (cntv > 64) cntv = 64;

    const int dd = k & 3;
    float wg0 = Wg[k*3+0], wg1 = Wg[k*3+1], wg2 = Wg[k*3+2];
    float alv = aat[dd],   arv = aat[4+dd];
    float b0i = bih0[k]    + bhh0[k];
    float b0f = bih0[32+k] + bhh0[32+k];
    float b0g = bih0[64+k] + bhh0[64+k];
    float b0o = bih0[96+k] + bhh0[96+k];
    float b1i = bih1[k]    + bhh1[k];
    float b1f = bih1[32+k] + bhh1[32+k];
    float b1g = bih1[64+k] + bhh1[64+k];
    float b1o = bih1[96+k] + bhh1[96+k];

    __syncthreads();

    float h0f[32], h1f[32];
    #pragma unroll
    for (int d = 0; d < 32; d++) { h0f[d] = 0.f; h1f[d] = 0.f; }
    float c0 = 0.f, c1 = 0.f;
    const size_t xrow = (size_t)(b*300 + i) * 36;

    for (int t = 0; t < 12; t++) {
        float gi = wg0*X[xrow + t*3 + 0] + wg1*X[xrow + t*3 + 1]
                 + wg2*X[xrow + t*3 + 2];
        float gl = gi * alv;
        gl += __shfl_xor(gl, 1, 64);
        gl += __shfl_xor(gl, 2, 64);

        float m = -1e30f, s = 0.f, acc = 0.f;
        for (int kk = 0; kk < cntv; kk++) {
            int v = (kk & 32) ? nb1 : nb0;
            int j = __shfl(v, lb + (kk & 31), 64);
            size_t xj = (size_t)(b*300 + j) * 36 + t*3;
            float gj = wg0*X[xj+0] + wg1*X[xj+1] + wg2*X[xj+2];
            float gr = gj * arv;
            gr += __shfl_xor(gr, 1, 64);
            gr += __shfl_xor(gr, 2, 64);
            float e = gl + gr;
            e = e > 0.f ? e : 0.2f*e;
            if (e > m) {
                float sc = __expf(m - e);
                s = s*sc + 1.f; acc = acc*sc + gj; m = e;
            } else {
                float wgt = __expf(e - m);
                s += wgt; acc += wgt*gj;
            }
        }
        float x_k = acc / s;
        float xf[32];
        #pragma unroll
        for (int d = 0; d < 32; d++) xf[d] = __shfl(x_k, lb + d, 64);
        lstm_step_fb(sW0i, sW0h, b0i, b0f, b0g, b0o, xf,  h0f, c0, k, lb);
        lstm_step_fb(sW1i, sW1h, b1i, b1f, b1g, b1o, h0f, h1f, c1, k, lb);
    }

    for (int r = k; r < 36; r += 32) {
        float a2 = fcb[r];
        #pragma unroll
        for (int c2 = 0; c2 < 16; c2++) {
            float2 u = *(const float2*)&fcW[r*32 + 2*c2];
            a2 += u.x*h1f[2*c2] + u.y*h1f[2*c2+1];
        }
        out[seq*36 + r] = a2;
    }
}

extern "C" void kernel_launch(void* const* d_in, const int* in_sizes, int n_in,
                              void* d_out, int out_size, void* d_ws, size_t ws_size,
                              hipStream_t stream)
{
    const float* A    = (const float*)d_in[0];
    const float* X    = (const float*)d_in[1];
    const float* Wg   = (const float*)d_in[2];
    const float* aat  = (const float*)d_in[3];
    const float* Wih0 = (const float*)d_in[4];
    const float* Whh0 = (const float*)d_in[5];
    const float* bih0 = (const float*)d_in[6];
    const float* bhh0 = (const float*)d_in[7];
    const float* Wih1 = (const float*)d_in[8];
    const float* Whh1 = (const float*)d_in[9];
    const float* bih1 = (const float*)d_in[10];
    const float* bhh1 = (const float*)d_in[11];
    const float* fcW  = (const float*)d_in[12];
    const float* fcb  = (const float*)d_in[13];
    float* out = (float*)d_out;

    // ws layout: cnt[300]+pad -> idx[300*64] -> hgat[2400*12*32]
    const size_t need = (320 + 300*64) * sizeof(int) + (size_t)2400*12*32*sizeof(float);
    if (ws_size >= need) {
        int*   cnt  = (int*)d_ws;
        int*   idx  = cnt + 320;
        float* hgat = (float*)(idx + 300*64);
        k_nbr  <<<300, 64,  0, stream>>>(A, cnt, idx);
        k_attn <<<600, 256, 0, stream>>>(X, Wg, aat, cnt, idx, hgat);
        k_lstm4<<<240, 512, 0, stream>>>(hgat, Wih0, Whh0, bih0, bhh0,
                                         Wih1, Whh1, bih1, bhh1, fcW, fcb, out);
    } else {
        k_fused_fb<<<300, 256, 0, stream>>>(A, X, Wg, aat,
                                            Wih0, Whh0, bih0, bhh0,
                                            Wih1, Whh1, bih1, bhh1,
                                            fcW, fcb, out);
    }
}

// Round 7
// 44.681 us; speedup vs baseline: 10.1332x; 1.1829x over previous
//
#include <hip/hip_runtime.h>

typedef __attribute__((ext_vector_type(8))) short s8v;   // 8 x bf16 (bit pattern)
typedef __attribute__((ext_vector_type(4))) float f4v;

__device__ __forceinline__ float sgm(float x) { return 1.f / (1.f + __expf(-x)); }
__device__ __forceinline__ float tanh_fast(float x) {
    float e = __expf(-2.f * fabsf(x));
    float t = (1.f - e) / (1.f + e);
    return copysignf(t, x);
}
// split f32 -> bf16 hi + bf16 lo (x ~= hi + lo, residual ~2^-17 |x|)
__device__ __forceinline__ void bsplit(float x, short& hi, short& lo) {
    unsigned u = __float_as_uint(x);
    unsigned hb = u & 0xffff0000u;
    hi = (short)(hb >> 16);
    float r = x - __uint_as_float(hb);
    lo = (short)(__float_as_uint(r) >> 16);
}

// ========== kernel 0: neighbor lists + folded attention vectors ==========
// blockIdx.x = i (300 blocks, 1 wave). Block 0 lanes 0..47 also compute
// walr[h*6 + {0..2}] = sum_d aat[d]*Wg[(h*4+d)*3+c]   (wal, c=0..2)
// walr[h*6 + {3..5}] = sum_d aat[4+d]*Wg[(h*4+d)*3+c] (war)
__global__ void k_nbr(const float* __restrict__ A, const float* __restrict__ Wg,
                      const float* __restrict__ aat,
                      int* __restrict__ cnt, int* __restrict__ idx,
                      float* __restrict__ walr)
{
    int i = blockIdx.x;
    int lane = threadIdx.x;
    if (i == 0 && lane < 48) {
        int h = lane / 6, q = lane - h*6;
        int cc = q % 3; bool right = q >= 3;
        float acc = 0.f;
        #pragma unroll
        for (int dd = 0; dd < 4; dd++)
            acc += aat[right ? 4+dd : dd] * Wg[(h*4+dd)*3 + cc];
        walr[lane] = acc;
    }
    int c = 0;
    for (int j0 = 0; j0 < 300; j0 += 64) {
        int j = j0 + lane;
        bool p = (j < 300) && (A[i*300 + j] != 0.f);
        unsigned long long m = __ballot(p);
        if (p) {
            int pos = __popcll(m & ((1ull << lane) - 1ull));
            if (c + pos < 64) idx[i*64 + c + pos] = j;
        }
        c += __popcll(m);
    }
    if (c > 64) c = 64;
    if (lane == 0) cnt[i] = c;
}

// ========== kernel 1: GAT attention, t-parallel ==========
// wave = one (seq, t) unit; 28800 units; lane = (h, j8): 8 heads x 8 j-slots.
__global__ __launch_bounds__(256, 4) void k_attn2(
    const float* __restrict__ X, const float* __restrict__ Wg,
    const int* __restrict__ cnt, const int* __restrict__ idx,
    const float* __restrict__ walr, float* __restrict__ hgat)
{
    int u = blockIdx.x * 4 + (threadIdx.x >> 6);     // 0..28799
    int lane = threadIdx.x & 63;
    int h = lane >> 3, j8 = lane & 7, d = j8 & 3;
    int seq = u / 12, t = u - seq*12;
    int b = seq / 300, i = seq - b*300;

    const float* wv = walr + h*6;
    float wal0 = wv[0], wal1 = wv[1], wal2 = wv[2];
    float war0 = wv[3], war1 = wv[4], war2 = wv[5];
    const float* wp = Wg + (h*4+d)*3;
    float wp0 = wp[0], wp1 = wp[1], wp2 = wp[2];

    int c = cnt[i];
    int jj[8];
    #pragma unroll
    for (int q = 0; q < 8; q++) jj[q] = idx[i*64 + q*8 + j8];

    const float* Xb = X + (size_t)b*300*36 + t*3;
    const float* Xi = Xb + i*36;
    float x0 = Xi[0], x1 = Xi[1], x2 = Xi[2];
    float gl = x0*wal0 + x1*wal1 + x2*wal2;

    float m = -1e30f, s = 0.f, a0 = 0.f, a1 = 0.f, a2 = 0.f;
    for (int q = 0; q*8 + j8 < c; q++) {
        int j = jj[q];
        const float* Xj = Xb + j*36;
        float y0 = Xj[0], y1 = Xj[1], y2 = Xj[2];
        float e = gl + y0*war0 + y1*war1 + y2*war2;
        e = e > 0.f ? e : 0.2f*e;                    // leaky_relu 0.2
        if (e > m) {
            float sc = __expf(m - e);
            s = s*sc + 1.f;
            a0 = a0*sc + y0; a1 = a1*sc + y1; a2 = a2*sc + y2;
            m = e;
        } else {
            float w = __expf(e - m);
            s += w;
            a0 += w*y0; a1 += w*y1; a2 += w*y2;
        }
    }
    #pragma unroll
    for (int off = 1; off <= 4; off <<= 1) {
        float m2 = __shfl_xor(m, off, 64);
        float s2 = __shfl_xor(s, off, 64);
        float b0 = __shfl_xor(a0, off, 64);
        float b1 = __shfl_xor(a1, off, 64);
        float b2 = __shfl_xor(a2, off, 64);
        float mo = fmaxf(m, m2);
        float w1 = __expf(m - mo), w2 = __expf(m2 - mo);
        s = s*w1 + s2*w2;
        a0 = a0*w1 + b0*w2; a1 = a1*w1 + b1*w2; a2 = a2*w1 + b2*w2;
        m = mo;
    }
    if (j8 < 4) {
        float o = (a0*wp0 + a1*wp1 + a2*wp2) / s;
        hgat[(size_t)u*32 + h*4 + d] = o;            // u = seq*12 + t
    }
}

// ========== kernel 2: LSTM x2 + FC via MFMA, software-pipelined ==========
// 240 blocks x 512 thr (8 waves), SQ=10 seqs/block (N padded to 16).
// Per phase: {z1(t), z0(t+1)} (12 MFMA) | barrier | {upd1(t), upd0(t+1)} | barrier.
// 26 barriers total (vs 48 unpipelined). Layout conventions HW-verified in round 6.
#define SQ 10

__device__ __forceinline__ void zcomp(const short* vh, const short* vl,
    const s8v (&ah)[2], const s8v (&al)[2], f4v bias, float* zdst,
    int boff, int g, int w, int n16)
{
    s8v bh0 = *(const s8v*)((const char*)vh + boff +      g*16);
    s8v bh1 = *(const s8v*)((const char*)vh + boff + 64 + g*16);
    s8v bl0 = *(const s8v*)((const char*)vl + boff +      g*16);
    s8v bl1 = *(const s8v*)((const char*)vl + boff + 64 + g*16);
    f4v acc = bias;
    acc = __builtin_amdgcn_mfma_f32_16x16x32_bf16(ah[0], bh0, acc, 0, 0, 0);
    acc = __builtin_amdgcn_mfma_f32_16x16x32_bf16(ah[1], bh1, acc, 0, 0, 0);
    acc = __builtin_amdgcn_mfma_f32_16x16x32_bf16(al[0], bh0, acc, 0, 0, 0);
    acc = __builtin_amdgcn_mfma_f32_16x16x32_bf16(al[1], bh1, acc, 0, 0, 0);
    acc = __builtin_amdgcn_mfma_f32_16x16x32_bf16(ah[0], bl0, acc, 0, 0, 0);
    acc = __builtin_amdgcn_mfma_f32_16x16x32_bf16(ah[1], bl1, acc, 0, 0, 0);
    *(f4v*)&zdst[n16*132 + w*16 + g*4] = acc;        // D: row = w*16+g*4+r, col = n16
}

__device__ __forceinline__ float cellupd(const float* zbp, int us, int uc, float& cst)
{
    float zi = zbp[us*132 + uc],      zf = zbp[us*132 + 32 + uc];
    float zg = zbp[us*132 + 64 + uc], zo = zbp[us*132 + 96 + uc];
    cst = sgm(zf)*cst + sgm(zi)*tanh_fast(zg);
    return sgm(zo)*tanh_fast(cst);
}

__global__ __launch_bounds__(512, 1) void k_lstm5(
    const float* __restrict__ hgat,
    const float* __restrict__ Wih0, const float* __restrict__ Whh0,
    const float* __restrict__ bih0, const float* __restrict__ bhh0,
    const float* __restrict__ Wih1, const float* __restrict__ Whh1,
    const float* __restrict__ bih1, const float* __restrict__ bhh1,
    const float* __restrict__ fcW,  const float* __restrict__ fcb,
    float* __restrict__ out)
{
    __shared__ __align__(16) short vh0[16*72], vl0[16*72];   // [seq][x(t) ; h0(t-1)]
    __shared__ __align__(16) short vh1[16*72], vl1[16*72];   // [seq][h0(t) ; h1(t-1)]
    __shared__ __align__(16) float zb0[16*132], zb1[16*132];
    __shared__ float sh1f[SQ*32];

    const int tid = threadIdx.x;
    const int w   = tid >> 6;        // wave 0..7
    const int l   = tid & 63;
    const int n16 = l & 15;          // A: m ; B/D: n (seq)
    const int g   = l >> 4;          // k-group 0..3
    const int zrow = w*16 + n16;

    // ---- A fragments (weights hi/lo), resident in VGPRs all kernel ----
    s8v a0h[2], a0l[2], a1h[2], a1l[2];
    {
        const float* s00 = Wih0 + zrow*32 + g*8;
        const float* s01 = Whh0 + zrow*32 + g*8;
        const float* s10 = Wih1 + zrow*32 + g*8;
        const float* s11 = Whh1 + zrow*32 + g*8;
        #pragma unroll
        for (int j = 0; j < 8; j++) {
            short hh, ll;
            bsplit(s00[j], hh, ll); a0h[0][j]=hh; a0l[0][j]=ll;
            bsplit(s01[j], hh, ll); a0h[1][j]=hh; a0l[1][j]=ll;
            bsplit(s10[j], hh, ll); a1h[0][j]=hh; a1l[0][j]=ll;
            bsplit(s11[j], hh, ll); a1h[1][j]=hh; a1l[1][j]=ll;
        }
    }
    f4v bias0, bias1;
    #pragma unroll
    for (int r = 0; r < 4; r++) {
        int rr = w*16 + g*4 + r;
        bias0[r] = bih0[rr] + bhh0[rr];
        bias1[r] = bih1[rr] + bhh1[rr];
    }

    const int us = tid >> 5, uc = tid & 31;
    const bool upd = tid < SQ*32;
    const int seq0 = blockIdx.x * SQ;
    const int boff = n16 * 144;

    if (upd) {
        short hh, ll;
        bsplit(hgat[(size_t)(seq0+us)*384 + uc], hh, ll);   // x(0)
        vh0[us*72 + uc] = hh;      vl0[us*72 + uc] = ll;
        vh0[us*72 + 32 + uc] = 0;  vl0[us*72 + 32 + uc] = 0;
        vh1[us*72 + uc] = 0;       vl1[us*72 + uc] = 0;
        vh1[us*72 + 32 + uc] = 0;  vl1[us*72 + 32 + uc] = 0;
    }
    __syncthreads();

    float c0 = 0.f, c1 = 0.f;

    // prologue: z0(0), upd0(0)
    zcomp(vh0, vl0, a0h, a0l, bias0, zb0, boff, g, w, n16);
    __syncthreads();
    if (upd) {
        float h0v = cellupd(zb0, us, uc, c0);
        short hh, ll; bsplit(h0v, hh, ll);
        vh0[us*72 + 32 + uc] = hh;  vl0[us*72 + 32 + uc] = ll;
        vh1[us*72 + uc]      = hh;  vl1[us*72 + uc]      = ll;
        bsplit(hgat[(size_t)(seq0+us)*384 + 32 + uc], hh, ll);  // x(1)
        vh0[us*72 + uc] = hh;  vl0[us*72 + uc] = ll;
    }
    __syncthreads();

    for (int t = 0; t < 12; t++) {
        zcomp(vh1, vl1, a1h, a1l, bias1, zb1, boff, g, w, n16);       // z1(t)
        if (t < 11)
            zcomp(vh0, vl0, a0h, a0l, bias0, zb0, boff, g, w, n16);   // z0(t+1)
        __syncthreads();
        if (upd) {
            float h1v = cellupd(zb1, us, uc, c1);                     // upd1(t)
            short hh, ll; bsplit(h1v, hh, ll);
            vh1[us*72 + 32 + uc] = hh;  vl1[us*72 + 32 + uc] = ll;
            if (t == 11) sh1f[us*32 + uc] = h1v;
            if (t < 11) {
                float h0v = cellupd(zb0, us, uc, c0);                 // upd0(t+1)
                bsplit(h0v, hh, ll);
                vh0[us*72 + 32 + uc] = hh;  vl0[us*72 + 32 + uc] = ll;
                vh1[us*72 + uc]      = hh;  vl1[us*72 + uc]      = ll;
                if (t + 2 < 12) {                                     // stage x(t+2)
                    bsplit(hgat[(size_t)(seq0+us)*384 + (t+2)*32 + uc], hh, ll);
                    vh0[us*72 + uc] = hh;  vl0[us*72 + uc] = ll;
                }
            }
        }
        __syncthreads();
    }

    // ---- FC: 360 outputs (10 seqs x 36) ----
    if (tid < SQ*36) {
        int s = tid / 36, r = tid - s*36;
        float acc = fcb[r];
        #pragma unroll
        for (int c4 = 0; c4 < 8; c4++) {
            float4 uv = *(const float4*)&fcW[r*32 + 4*c4];
            acc += uv.x*sh1f[s*32+4*c4+0] + uv.y*sh1f[s*32+4*c4+1]
                 + uv.z*sh1f[s*32+4*c4+2] + uv.w*sh1f[s*32+4*c4+3];
        }
        out[(seq0 + s)*36 + r] = acc;
    }
}

// =================== fallback (round-3 fused kernel, zero-ws, known-good) ===================
__device__ __forceinline__ void lstm_step_fb(
    const float* __restrict__ sWi, const float* __restrict__ sWh,
    float bzi, float bzf, float bzg, float bzo,
    const float (&xf)[32], float (&hf)[32], float& cst, int k, int lb)
{
    float zi = bzi, zf = bzf, zg = bzg, zo = bzo;
    const int sw = k & 15;
    #pragma unroll
    for (int c2 = 0; c2 < 16; c2++) {
        const int col = 2 * (c2 ^ sw);
        float xa = xf[2*c2], xb = xf[2*c2+1];
        float ha = hf[2*c2], hb = hf[2*c2+1];
        float2 wiA = *(const float2*)&sWi[(0  + k)*32 + col];
        float2 whA = *(const float2*)&sWh[(0  + k)*32 + col];
        zi += wiA.x*xa + wiA.y*xb + whA.x*ha + whA.y*hb;
        float2 wiB = *(const float2*)&sWi[(32 + k)*32 + col];
        float2 whB = *(const float2*)&sWh[(32 + k)*32 + col];
        zf += wiB.x*xa + wiB.y*xb + whB.x*ha + whB.y*hb;
        float2 wiC = *(const float2*)&sWi[(64 + k)*32 + col];
        float2 whC = *(const float2*)&sWh[(64 + k)*32 + col];
        zg += wiC.x*xa + wiC.y*xb + whC.x*ha + whC.y*hb;
        float2 wiD = *(const float2*)&sWi[(96 + k)*32 + col];
        float2 whD = *(const float2*)&sWh[(96 + k)*32 + col];
        zo += wiD.x*xa + wiD.y*xb + whD.x*ha + whD.y*hb;
    }
    float ig = sgm(zi)*tanhf(zg);
    cst = sgm(zf)*cst + ig;
    float hl = sgm(zo)*tanhf(cst);
    #pragma unroll
    for (int d = 0; d < 32; d++) hf[d] = __shfl(hl, lb + d, 64);
}

__global__ __launch_bounds__(256) void k_fused_fb(
    const float* __restrict__ A,    const float* __restrict__ X,
    const float* __restrict__ Wg,   const float* __restrict__ aat,
    const float* __restrict__ Wih0, const float* __restrict__ Whh0,
    const float* __restrict__ bih0, const float* __restrict__ bhh0,
    const float* __restrict__ Wih1, const float* __restrict__ Whh1,
    const float* __restrict__ bih1, const float* __restrict__ bhh1,
    const float* __restrict__ fcW,  const float* __restrict__ fcb,
    float* __restrict__ out)
{
    __shared__ float sW0i[4096], sW0h[4096], sW1i[4096], sW1h[4096];
    const int tid = threadIdx.x;
    for (int x2 = tid; x2 < 2048; x2 += 256) {
        int r = x2 >> 4, p = x2 & 15;
        int o = r*32 + 2*(p ^ (r & 15));
        *(float2*)&sW0i[o] = *(const float2*)&Wih0[r*32 + 2*p];
        *(float2*)&sW0h[o] = *(const float2*)&Whh0[r*32 + 2*p];
        *(float2*)&sW1i[o] = *(const float2*)&Wih1[r*32 + 2*p];
        *(float2*)&sW1h[o] = *(const float2*)&Whh1[r*32 + 2*p];
    }
    const int w   = tid >> 5;
    const int k   = tid & 31;
    const int lb  = tid & 32;
    const int seq = blockIdx.x * 8 + w;
    const int b   = seq / 300, i = seq % 300;

    int nb0 = 0, nb1 = 0, cntv = 0;
    for (int j0 = 0; j0 < 300; j0 += 32) {
        int j = j0 + k;
        bool p = (j < 300) && (A[i*300 + j] != 0.f);
        unsigned long long m64 = __ballot(p);
        unsigned mm = (unsigned)(m64 >> lb);
        while (mm) {
            int bpos = __ffs(mm) - 1;
            if ((cntv & 31) == k && cntv < 64) {
                if (cntv & 32) nb1 = j0 + bpos; else nb0 = j0 + bpos;
            }
            cntv++;
            mm &= mm - 1;
        }
    }
    if (cntv > 64) cntv = 64;

    const int dd = k & 3;
    float wg0 = Wg[k*3+0], wg1 = Wg[k*3+1], wg2 = Wg[k*3+2];
    float alv = aat[dd],   arv = aat[4+dd];
    float b0i = bih0[k]    + bhh0[k];
    float b0f = bih0[32+k] + bhh0[32+k];
    float b0g = bih0[64+k] + bhh0[64+k];
    float b0o = bih0[96+k] + bhh0[96+k];
    float b1i = bih1[k]    + bhh1[k];
    float b1f = bih1[32+k] + bhh1[32+k];
    float b1g = bih1[64+k] + bhh1[64+k];
    float b1o = bih1[96+k] + bhh1[96+k];

    __syncthreads();

    float h0f[32], h1f[32];
    #pragma unroll
    for (int d = 0; d < 32; d++) { h0f[d] = 0.f; h1f[d] = 0.f; }
    float c0 = 0.f, c1 = 0.f;
    const size_t xrow = (size_t)(b*300 + i) * 36;

    for (int t = 0; t < 12; t++) {
        float gi = wg0*X[xrow + t*3 + 0] + wg1*X[xrow + t*3 + 1]
                 + wg2*X[xrow + t*3 + 2];
        float gl = gi * alv;
        gl += __shfl_xor(gl, 1, 64);
        gl += __shfl_xor(gl, 2, 64);

        float m = -1e30f, s = 0.f, acc = 0.f;
        for (int kk = 0; kk < cntv; kk++) {
            int v = (kk & 32) ? nb1 : nb0;
            int j = __shfl(v, lb + (kk & 31), 64);
            size_t xj = (size_t)(b*300 + j) * 36 + t*3;
            float gj = wg0*X[xj+0] + wg1*X[xj+1] + wg2*X[xj+2];
            float gr = gj * arv;
            gr += __shfl_xor(gr, 1, 64);
            gr += __shfl_xor(gr, 2, 64);
            float e = gl + gr;
            e = e > 0.f ? e : 0.2f*e;
            if (e > m) {
                float sc = __expf(m - e);
                s = s*sc + 1.f; acc = acc*sc + gj; m = e;
            } else {
                float wgt = __expf(e - m);
                s += wgt; acc += wgt*gj;
            }
        }
        float x_k = acc / s;
        float xf[32];
        #pragma unroll
        for (int d = 0; d < 32; d++) xf[d] = __shfl(x_k, lb + d, 64);
        lstm_step_fb(sW0i, sW0h, b0i, b0f, b0g, b0o, xf,  h0f, c0, k, lb);
        lstm_step_fb(sW1i, sW1h, b1i, b1f, b1g, b1o, h0f, h1f, c1, k, lb);
    }

    for (int r = k; r < 36; r += 32) {
        float a2 = fcb[r];
        #pragma unroll
        for (int c2 = 0; c2 < 16; c2++) {
            float2 u = *(const float2*)&fcW[r*32 + 2*c2];
            a2 += u.x*h1f[2*c2] + u.y*h1f[2*c2+1];
        }
        out[seq*36 + r] = a2;
    }
}

extern "C" void kernel_launch(void* const* d_in, const int* in_sizes, int n_in,
                              void* d_out, int out_size, void* d_ws, size_t ws_size,
                              hipStream_t stream)
{
    const float* A    = (const float*)d_in[0];
    const float* X    = (const float*)d_in[1];
    const float* Wg   = (const float*)d_in[2];
    const float* aat  = (const float*)d_in[3];
    const float* Wih0 = (const float*)d_in[4];
    const float* Whh0 = (const float*)d_in[5];
    const float* bih0 = (const float*)d_in[6];
    const float* bhh0 = (const float*)d_in[7];
    const float* Wih1 = (const float*)d_in[8];
    const float* Whh1 = (const float*)d_in[9];
    const float* bih1 = (const float*)d_in[10];
    const float* bhh1 = (const float*)d_in[11];
    const float* fcW  = (const float*)d_in[12];
    const float* fcb  = (const float*)d_in[13];
    float* out = (float*)d_out;

    // ws layout: cnt[320 ints] | idx[300*64 ints] | walr[48 f + pad 16] | hgat[2400*384 f]
    const size_t need = (320 + 300*64) * sizeof(int) + 64*sizeof(float)
                      + (size_t)2400*384*sizeof(float);
    if (ws_size >= need) {
        int*   cnt  = (int*)d_ws;
        int*   idx  = cnt + 320;
        float* walr = (float*)(idx + 300*64);
        float* hgat = walr + 64;
        k_nbr  <<<300,  64,  0, stream>>>(A, Wg, aat, cnt, idx, walr);
        k_attn2<<<7200, 256, 0, stream>>>(X, Wg, cnt, idx, walr, hgat);
        k_lstm5<<<240,  512, 0, stream>>>(hgat, Wih0, Whh0, bih0, bhh0,
                                          Wih1, Whh1, bih1, bhh1, fcW, fcb, out);
    } else {
        k_fused_fb<<<300, 256, 0, stream>>>(A, X, Wg, aat,
                                            Wih0, Whh0, bih0, bhh0,
                                            Wih1, Whh1, bih1, bhh1,
                                            fcW, fcb, out);
    }
}

// Round 8
// 43.997 us; speedup vs baseline: 10.2909x; 1.0156x over previous
//
#include <hip/hip_runtime.h>

typedef __attribute__((ext_vector_type(8))) short s8v;   // 8 x bf16 (bit pattern)
typedef __attribute__((ext_vector_type(4))) float f4v;

__device__ __forceinline__ float sgm(float x) { return 1.f / (1.f + __expf(-x)); }
__device__ __forceinline__ float tanh_fast(float x) {
    float e = __expf(-2.f * fabsf(x));
    float t = (1.f - e) / (1.f + e);
    return copysignf(t, x);
}
// split f32 -> bf16 hi + bf16 lo (x ~= hi + lo, residual ~2^-17 |x|)
__device__ __forceinline__ void bsplit(float x, short& hi, short& lo) {
    unsigned u = __float_as_uint(x);
    unsigned hb = u & 0xffff0000u;
    hi = (short)(hb >> 16);
    float r = x - __uint_as_float(hb);
    lo = (short)(__float_as_uint(r) >> 16);
}

#define SQ 10   // seqs per block; 240 blocks x 10 = 2400

// z(128x16) = W(128x64) @ v(64x16), bf16 hi/lo split: Wh*vh + Wl*vh + Wh*vl.
// Layout conventions HW-verified in rounds 6/7 (absmax 0.0039 vs np ref).
__device__ __forceinline__ void zcomp(const short* vh, const short* vl,
    const s8v (&ah)[2], const s8v (&al)[2], f4v bias, float* zdst,
    int boff, int g, int w, int n16)
{
    s8v bh0 = *(const s8v*)((const char*)vh + boff +      g*16);
    s8v bh1 = *(const s8v*)((const char*)vh + boff + 64 + g*16);
    s8v bl0 = *(const s8v*)((const char*)vl + boff +      g*16);
    s8v bl1 = *(const s8v*)((const char*)vl + boff + 64 + g*16);
    f4v acc = bias;
    acc = __builtin_amdgcn_mfma_f32_16x16x32_bf16(ah[0], bh0, acc, 0, 0, 0);
    acc = __builtin_amdgcn_mfma_f32_16x16x32_bf16(ah[1], bh1, acc, 0, 0, 0);
    acc = __builtin_amdgcn_mfma_f32_16x16x32_bf16(al[0], bh0, acc, 0, 0, 0);
    acc = __builtin_amdgcn_mfma_f32_16x16x32_bf16(al[1], bh1, acc, 0, 0, 0);
    acc = __builtin_amdgcn_mfma_f32_16x16x32_bf16(ah[0], bl0, acc, 0, 0, 0);
    acc = __builtin_amdgcn_mfma_f32_16x16x32_bf16(ah[1], bl1, acc, 0, 0, 0);
    *(f4v*)&zdst[n16*132 + w*16 + g*4] = acc;        // D: row = w*16+g*4+r, col = n16
}

__device__ __forceinline__ float cellupd(const float* zbp, int us, int uc, float& cst)
{
    float zi = zbp[us*132 + uc],      zf = zbp[us*132 + 32 + uc];
    float zg = zbp[us*132 + 64 + uc], zo = zbp[us*132 + 96 + uc];
    cst = sgm(zf)*cst + sgm(zi)*tanh_fast(zg);
    return sgm(zo)*tanh_fast(cst);
}

// ===== single fused kernel: nbr lists + GAT attention + LSTM x2 (MFMA) + FC =====
// 240 blocks x 512 thr (8 waves). Zero d_ws use.
__global__ __launch_bounds__(512, 1) void k_stgat(
    const float* __restrict__ A,    const float* __restrict__ X,
    const float* __restrict__ Wg,   const float* __restrict__ aat,
    const float* __restrict__ Wih0, const float* __restrict__ Whh0,
    const float* __restrict__ bih0, const float* __restrict__ bhh0,
    const float* __restrict__ Wih1, const float* __restrict__ Whh1,
    const float* __restrict__ bih1, const float* __restrict__ bhh1,
    const float* __restrict__ fcW,  const float* __restrict__ fcb,
    float* __restrict__ out)
{
    __shared__ int   snbr[SQ][64];
    __shared__ int   scnt[SQ];
    __shared__ float shg[SQ*384];                            // local hgat (15 KB)
    __shared__ __align__(16) short vh0[16*72], vl0[16*72];   // [seq][x(t) ; h0(t-1)]
    __shared__ __align__(16) short vh1[16*72], vl1[16*72];   // [seq][h0(t) ; h1(t-1)]
    __shared__ __align__(16) float zb0[16*132], zb1[16*132];
    __shared__ float sh1f[SQ*32];

    const int tid  = threadIdx.x;
    const int w    = tid >> 6;        // wave 0..7
    const int l    = tid & 63;
    const int seq0 = blockIdx.x * SQ;

    // ---------- phase A: neighbor lists for this block's <=10 distinct i rows ----------
    for (int r = w; r < SQ; r += 8) {
        int i = (seq0 + r) % 300;
        int c = 0;
        for (int j0 = 0; j0 < 300; j0 += 64) {
            int j = j0 + l;
            bool p = (j < 300) && (A[i*300 + j] != 0.f);
            unsigned long long m = __ballot(p);
            if (p) {
                int pos = __popcll(m & ((1ull << l) - 1ull));
                if (c + pos < 64) snbr[r][c + pos] = j;
            }
            c += __popcll(m);
        }
        if (c > 64) c = 64;
        if (l == 0) scnt[r] = c;
    }

    // ---------- LSTM weight A-fragments (global loads overlap phases A/B) ----------
    const int n16  = l & 15;          // A: m within tile ; B/D: n (seq)
    const int g    = l >> 4;          // k-group 0..3
    const int zrow = w*16 + n16;
    s8v a0h[2], a0l[2], a1h[2], a1l[2];
    {
        const float* s00 = Wih0 + zrow*32 + g*8;
        const float* s01 = Whh0 + zrow*32 + g*8;
        const float* s10 = Wih1 + zrow*32 + g*8;
        const float* s11 = Whh1 + zrow*32 + g*8;
        #pragma unroll
        for (int j = 0; j < 8; j++) {
            short hh, ll;
            bsplit(s00[j], hh, ll); a0h[0][j]=hh; a0l[0][j]=ll;
            bsplit(s01[j], hh, ll); a0h[1][j]=hh; a0l[1][j]=ll;
            bsplit(s10[j], hh, ll); a1h[0][j]=hh; a1l[0][j]=ll;
            bsplit(s11[j], hh, ll); a1h[1][j]=hh; a1l[1][j]=ll;
        }
    }
    f4v bias0, bias1;
    #pragma unroll
    for (int r = 0; r < 4; r++) {
        int rr = w*16 + g*4 + r;
        bias0[r] = bih0[rr] + bhh0[rr];
        bias1[r] = bih1[rr] + bhh1[rr];
    }

    __syncthreads();

    // ---------- phase B: GAT attention, 120 (seq,t) units; wave w does 15 ----------
    {
        const int h = l >> 3, j8 = l & 7, d = j8 & 3;
        float wal0=0.f, wal1=0.f, wal2=0.f, war0=0.f, war1=0.f, war2=0.f;
        #pragma unroll
        for (int dd = 0; dd < 4; dd++) {
            float av = aat[dd], bv = aat[4+dd];
            const float* wr = Wg + (h*4+dd)*3;
            wal0 += wr[0]*av; wal1 += wr[1]*av; wal2 += wr[2]*av;
            war0 += wr[0]*bv; war1 += wr[1]*bv; war2 += wr[2]*bv;
        }
        const float* wp = Wg + (h*4+d)*3;
        float wp0 = wp[0], wp1 = wp[1], wp2 = wp[2];

        for (int q = 0; q < 15; q++) {
            int u  = w*15 + q;                 // 0..119
            int us = u / 12, t = u - us*12;
            int seq = seq0 + us;
            int b = seq / 300, i = seq - b*300;
            int c = scnt[us];

            const float* Xb = X + (size_t)b*300*36 + t*3;
            const float* Xi = Xb + i*36;
            float gl = Xi[0]*wal0 + Xi[1]*wal1 + Xi[2]*wal2;

            float m = -1e30f, s = 0.f, a0 = 0.f, a1 = 0.f, a2 = 0.f;
            for (int kk = j8; kk < c; kk += 8) {
                int j = snbr[us][kk];
                const float* Xj = Xb + j*36;
                float y0 = Xj[0], y1 = Xj[1], y2 = Xj[2];
                float e = gl + y0*war0 + y1*war1 + y2*war2;
                e = e > 0.f ? e : 0.2f*e;      // leaky_relu 0.2
                if (e > m) {
                    float sc = __expf(m - e);
                    s = s*sc + 1.f;
                    a0 = a0*sc + y0; a1 = a1*sc + y1; a2 = a2*sc + y2;
                    m = e;
                } else {
                    float wt = __expf(e - m);
                    s += wt;
                    a0 += wt*y0; a1 += wt*y1; a2 += wt*y2;
                }
            }
            #pragma unroll
            for (int off = 1; off <= 4; off <<= 1) {
                float m2 = __shfl_xor(m, off, 64);
                float s2 = __shfl_xor(s, off, 64);
                float b0 = __shfl_xor(a0, off, 64);
                float b1 = __shfl_xor(a1, off, 64);
                float b2 = __shfl_xor(a2, off, 64);
                float mo = fmaxf(m, m2);
                float w1 = __expf(m - mo), w2 = __expf(m2 - mo);
                s = s*w1 + s2*w2;
                a0 = a0*w1 + b0*w2; a1 = a1*w1 + b1*w2; a2 = a2*w1 + b2*w2;
                m = mo;
            }
            if (j8 < 4)
                shg[us*384 + t*32 + h*4 + d] = (a0*wp0 + a1*wp1 + a2*wp2) / s;
        }
    }
    __syncthreads();

    // ---------- phase C: software-pipelined MFMA LSTM + FC ----------
    const int us = tid >> 5, uc = tid & 31;
    const bool upd = tid < SQ*32;
    const int boff = n16 * 144;

    if (upd) {
        short hh, ll;
        bsplit(shg[us*384 + uc], hh, ll);                   // x(0)
        vh0[us*72 + uc] = hh;      vl0[us*72 + uc] = ll;
        vh0[us*72 + 32 + uc] = 0;  vl0[us*72 + 32 + uc] = 0;
        vh1[us*72 + uc] = 0;       vl1[us*72 + uc] = 0;
        vh1[us*72 + 32 + uc] = 0;  vl1[us*72 + 32 + uc] = 0;
    }
    __syncthreads();

    float c0 = 0.f, c1 = 0.f;

    // prologue: z0(0), upd0(0)
    zcomp(vh0, vl0, a0h, a0l, bias0, zb0, boff, g, w, n16);
    __syncthreads();
    if (upd) {
        float h0v = cellupd(zb0, us, uc, c0);
        short hh, ll; bsplit(h0v, hh, ll);
        vh0[us*72 + 32 + uc] = hh;  vl0[us*72 + 32 + uc] = ll;
        vh1[us*72 + uc]      = hh;  vl1[us*72 + uc]      = ll;
        bsplit(shg[us*384 + 32 + uc], hh, ll);              // x(1)
        vh0[us*72 + uc] = hh;  vl0[us*72 + uc] = ll;
    }
    __syncthreads();

    for (int t = 0; t < 12; t++) {
        zcomp(vh1, vl1, a1h, a1l, bias1, zb1, boff, g, w, n16);       // z1(t)
        if (t < 11)
            zcomp(vh0, vl0, a0h, a0l, bias0, zb0, boff, g, w, n16);   // z0(t+1)
        __syncthreads();
        if (upd) {
            float h1v = cellupd(zb1, us, uc, c1);                     // upd1(t)
            short hh, ll; bsplit(h1v, hh, ll);
            vh1[us*72 + 32 + uc] = hh;  vl1[us*72 + 32 + uc] = ll;
            if (t == 11) sh1f[us*32 + uc] = h1v;
            if (t < 11) {
                float h0v = cellupd(zb0, us, uc, c0);                 // upd0(t+1)
                bsplit(h0v, hh, ll);
                vh0[us*72 + 32 + uc] = hh;  vl0[us*72 + 32 + uc] = ll;
                vh1[us*72 + uc]      = hh;  vl1[us*72 + uc]      = ll;
                if (t + 2 < 12) {                                     // stage x(t+2)
                    bsplit(shg[us*384 + (t+2)*32 + uc], hh, ll);
                    vh0[us*72 + uc] = hh;  vl0[us*72 + uc] = ll;
                }
            }
        }
        __syncthreads();
    }

    // ---- FC: 360 outputs (10 seqs x 36) ----
    if (tid < SQ*36) {
        int s = tid / 36, r = tid - s*36;
        float acc = fcb[r];
        #pragma unroll
        for (int c4 = 0; c4 < 8; c4++) {
            float4 uv = *(const float4*)&fcW[r*32 + 4*c4];
            acc += uv.x*sh1f[s*32+4*c4+0] + uv.y*sh1f[s*32+4*c4+1]
                 + uv.z*sh1f[s*32+4*c4+2] + uv.w*sh1f[s*32+4*c4+3];
        }
        out[(seq0 + s)*36 + r] = acc;
    }
}

extern "C" void kernel_launch(void* const* d_in, const int* in_sizes, int n_in,
                              void* d_out, int out_size, void* d_ws, size_t ws_size,
                              hipStream_t stream)
{
    const float* A    = (const float*)d_in[0];
    const float* X    = (const float*)d_in[1];
    const float* Wg   = (const float*)d_in[2];
    const float* aat  = (const float*)d_in[3];
    const float* Wih0 = (const float*)d_in[4];
    const float* Whh0 = (const float*)d_in[5];
    const float* bih0 = (const float*)d_in[6];
    const float* bhh0 = (const float*)d_in[7];
    const float* Wih1 = (const float*)d_in[8];
    const float* Whh1 = (const float*)d_in[9];
    const float* bih1 = (const float*)d_in[10];
    const float* bhh1 = (const float*)d_in[11];
    const float* fcW  = (const float*)d_in[12];
    const float* fcb  = (const float*)d_in[13];
    float* out = (float*)d_out;

    k_stgat<<<240, 512, 0, stream>>>(A, X, Wg, aat,
                                     Wih0, Whh0, bih0, bhh0,
                                     Wih1, Whh1, bih1, bhh1,
                                     fcW, fcb, out);
}